// Round 3
// baseline (1581.714 us; speedup 1.0000x reference)
//
#include <hip/hip_runtime.h>
#include <hip/hip_bf16.h>
#include <cmath>

#define USER_NUM 52643
#define ITEM_NUM 91599
#define NNODE (USER_NUM + ITEM_NUM)   // 144242
#define DDIM 64

typedef unsigned int uint32;
typedef unsigned short ushort16;

__device__ __forceinline__ ushort16 f2bf(float f) {
    uint32 u = __float_as_uint(f);
    u += 0x7fffu + ((u >> 16) & 1u);   // round-to-nearest-even
    return (ushort16)(u >> 16);
}

// ---------------- small utility kernels ----------------

__global__ void zero_ints_kernel(int* __restrict__ p, int n) {
    int i = blockIdx.x * 256 + threadIdx.x;
    if (i < n) p[i] = 0;
}

__global__ void init_loss_kernel(float* __restrict__ out, int loss_idx) {
    if (threadIdx.x == 0) out[loss_idx] = 0.0f;
}

// ---------------- CSR build ----------------

__global__ void hist_kernel(const int* __restrict__ rows, int* __restrict__ deg, int E) {
    int e = blockIdx.x * 256 + threadIdx.x;
    if (e < E) atomicAdd(&deg[rows[e]], 1);
}

__global__ void block_sums_kernel(const int* __restrict__ deg, int* __restrict__ bsums, int n) {
    int t = threadIdx.x;                 // 1024 threads
    int base = blockIdx.x * 2048;
    int s = 0;
    for (int i = t; i < 2048; i += 1024) {
        int idx = base + i;
        if (idx < n) s += deg[idx];
    }
    for (int off = 32; off; off >>= 1) s += __shfl_xor(s, off);
    __shared__ int ws[16];
    int lane = t & 63, wid = t >> 6;
    if (lane == 0) ws[wid] = s;
    __syncthreads();
    if (t < 64) {
        int v = (t < 16) ? ws[t] : 0;
        for (int off = 32; off; off >>= 1) v += __shfl_xor(v, off);
        if (t == 0) bsums[blockIdx.x] = v;
    }
}

__global__ void scan_bsums_kernel(int* __restrict__ bsums, int nb) {
    if (threadIdx.x == 0 && blockIdx.x == 0) {
        int acc = 0;
        for (int i = 0; i < nb; ++i) { int v = bsums[i]; bsums[i] = acc; acc += v; }
    }
}

__global__ void block_scan_kernel(const int* __restrict__ deg, const int* __restrict__ bsums,
                                  int* __restrict__ row_ptr, int n) {
    int t = threadIdx.x;                  // 1024 threads, 2 elems each
    int lane = t & 63, wid = t >> 6;
    int base = blockIdx.x * 2048;
    int i0 = base + 2 * t, i1 = i0 + 1;
    int d0 = (i0 < n) ? deg[i0] : 0;
    int d1 = (i1 < n) ? deg[i1] : 0;
    int s = d0 + d1;
    int v = s;
    #pragma unroll
    for (int delta = 1; delta < 64; delta <<= 1) {
        int src = lane - delta;
        int tmp = __shfl(v, (src < 0) ? lane : src);
        v += (src < 0) ? 0 : tmp;
    }
    __shared__ int wsum[16];
    __shared__ int woff[16];
    if (lane == 63) wsum[wid] = v;
    __syncthreads();
    if (t < 64) {
        int orig = (t < 16) ? wsum[t] : 0;
        int w = orig;
        #pragma unroll
        for (int delta = 1; delta < 64; delta <<= 1) {
            int src = t - delta;
            int tmp = __shfl(w, (src < 0) ? t : src);
            w += (src < 0) ? 0 : tmp;
        }
        if (t < 16) woff[t] = w - orig;   // exclusive
    }
    __syncthreads();
    int off = bsums[blockIdx.x] + woff[wid];
    int excl = off + v - s;
    if (i0 < n) row_ptr[i0 + 1] = excl + d0;
    if (i1 < n) row_ptr[i1 + 1] = excl + d0 + d1;
    if (blockIdx.x == 0 && t == 0) row_ptr[0] = 0;
}

__global__ void scatter_kernel(const int* __restrict__ rows, const int* __restrict__ cols,
                               const float* __restrict__ vals, const int* __restrict__ row_ptr,
                               int* __restrict__ cnt, uint2* __restrict__ edges, int E) {
    int e = blockIdx.x * 256 + threadIdx.x;
    if (e < E) {
        int r = rows[e];
        int pos = row_ptr[r] + atomicAdd(&cnt[r], 1);
        edges[pos] = make_uint2((uint32)cols[e], __float_as_uint(vals[e]));
    }
}

// ---------------- fused GNN layer ----------------
// wave-per-row, grid-stride; lane = feature dim; f32 gathers (4B/lane, coalesced);
// bf16-packed W in LDS (16.9 KB -> 8 blocks/CU). SPLIT=1: x from split user/item tables.

template <int SPLIT>
__global__ __launch_bounds__(256, 8) void gnn_layer_kernel(
    const float* __restrict__ xA, const float* __restrict__ xB,
    const int* __restrict__ row_ptr, const uint2* __restrict__ edges,
    const float* __restrict__ W, const float* __restrict__ b,
    const float* __restrict__ Wi, const float* __restrict__ bi,
    float* __restrict__ out)
{
    __shared__ uint32 Wt2[64 * 65];   // Wt2[k*65+j] = pack(bf16 Wi[j][k] << 16 | bf16 W[j][k])
    __shared__ float bias_s[64];
    int tid = threadIdx.x;
    int lane = tid & 63;
    int wid = tid >> 6;

    for (int i = tid; i < 64 * 64; i += 256) {
        int j = i >> 6, k = i & 63;          // W[j][k]
        Wt2[k * 65 + j] = ((uint32)f2bf(Wi[i]) << 16) | (uint32)f2bf(W[i]);
    }
    if (tid < 64) bias_s[tid] = b[tid] + bi[tid];
    __syncthreads();

    for (int row = blockIdx.x * 4 + wid; row < NNODE; row += gridDim.x * 4) {
        int e0 = __builtin_amdgcn_readfirstlane(row_ptr[row]);
        int e1 = __builtin_amdgcn_readfirstlane(row_ptr[row + 1]);
        float acc1 = 0.0f, acc2 = 0.0f;

        for (int e = e0; e < e1; e += 8) {
            float xv[8], vv[8];
            #pragma unroll
            for (int u = 0; u < 8; ++u) {
                int ee = e + u;
                int ec = (ee < e1) ? ee : (e1 - 1);      // clamp: no OOB
                uint2 ed = edges[ec];                     // wave-uniform -> broadcast
                float v = __uint_as_float(ed.y);
                vv[u] = (ee < e1) ? v : 0.0f;
                const float* xp;
                if (SPLIT) xp = ((int)ed.x < USER_NUM) ? (xA + ((size_t)ed.x << 6))
                                                       : (xB + (((size_t)ed.x - USER_NUM) << 6));
                else       xp = xA + ((size_t)ed.x << 6);
                xv[u] = xp[lane];
            }
            #pragma unroll
            for (int u = 0; u < 8; ++u) {
                acc1 = fmaf(vv[u], xv[u], acc1);
                acc2 = fmaf(vv[u], xv[u] * xv[u], acc2);
            }
        }

        float xr;
        if (SPLIT) xr = (row < USER_NUM) ? xA[((size_t)row << 6) + lane]
                                         : xB[(((size_t)row - USER_NUM) << 6) + lane];
        else       xr = xA[((size_t)row << 6) + lane];

        float p1 = acc1 + xr;    // (L + I) @ x
        float p2 = acc2;         // L @ (x*x)

        float oj = bias_s[lane];
        #pragma unroll
        for (int k = 0; k < 64; ++k) {
            float s1 = __shfl(p1, k);
            float s2 = __shfl(p2, k);
            uint32 w2 = Wt2[k * 65 + lane];
            oj = fmaf(s1, __uint_as_float(w2 << 16), oj);
            oj = fmaf(s2, __uint_as_float(w2 & 0xffff0000u), oj);
        }
        oj = fmaxf(oj, 0.0f);
        out[((size_t)row << 6) + lane] = oj;
    }
}

// ---------------- scoring + loss ----------------

__global__ void score_kernel(const int* __restrict__ user, const int* __restrict__ item_i,
                             const int* __restrict__ item_j,
                             const float* __restrict__ eu, const float* __restrict__ ei,
                             const float* __restrict__ g1, const float* __restrict__ g2,
                             float* __restrict__ out, int B)
{
    int t = blockIdx.x * 256 + threadIdx.x;
    int w = t >> 6;
    int lane = t & 63;
    if (w >= B) return;

    int u  = user[w];
    int i0 = item_i[w];
    int j0 = item_j[w];
    int ii = USER_NUM + i0;
    int jj = USER_NUM + j0;

    float e0u = eu[(size_t)u  * DDIM + lane];
    float e0i = ei[(size_t)i0 * DDIM + lane];
    float e0j = ei[(size_t)j0 * DDIM + lane];
    float g1u = g1[(size_t)u  * DDIM + lane];
    float g1i = g1[(size_t)ii * DDIM + lane];
    float g1j = g1[(size_t)jj * DDIM + lane];
    float g2u = g2[(size_t)u  * DDIM + lane];
    float g2i = g2[(size_t)ii * DDIM + lane];
    float g2j = g2[(size_t)jj * DDIM + lane];

    float di = e0u * e0i + g1u * g1i + g2u * g2i;
    float dj = e0u * e0j + g1u * g1j + g2u * g2j;
    for (int off = 32; off; off >>= 1) {
        di += __shfl_xor(di, off);
        dj += __shfl_xor(dj, off);
    }
    if (lane == 0) {
        out[w] = di;
        out[B + w] = dj;
        float x = di - dj;
        float sp = fmaxf(-x, 0.0f) + log1pf(expf(-fabsf(x)));   // softplus(-x)
        atomicAdd(&out[2 * B], sp);
    }
}

// ---------------- launch ----------------

extern "C" void kernel_launch(void* const* d_in, const int* in_sizes, int n_in,
                              void* d_out, int out_size, void* d_ws, size_t ws_size,
                              hipStream_t stream) {
    const int*   user       = (const int*)d_in[0];
    const int*   item_i     = (const int*)d_in[1];
    const int*   item_j     = (const int*)d_in[2];
    const int*   rows       = (const int*)d_in[3];
    const int*   cols       = (const int*)d_in[4];
    const float* vals       = (const float*)d_in[5];
    const float* embed_user = (const float*)d_in[6];
    const float* embed_item = (const float*)d_in[7];
    const float* W1  = (const float*)d_in[8];
    const float* b1  = (const float*)d_in[9];
    const float* Wi1 = (const float*)d_in[10];
    const float* bi1 = (const float*)d_in[11];
    const float* W2  = (const float*)d_in[12];
    const float* b2  = (const float*)d_in[13];
    const float* Wi2 = (const float*)d_in[14];
    const float* bi2 = (const float*)d_in[15];

    int B = in_sizes[0];
    int E = in_sizes[3];
    float* out = (float*)d_out;

    char* ws = (char*)d_ws;
    size_t off = 0;
    auto alloc = [&](size_t bytes) -> void* {
        void* p = ws + off;
        off += (bytes + 255) & ~(size_t)255;
        return p;
    };
    float*     g1      = (float*)alloc((size_t)NNODE * DDIM * 4);
    float*     g2      = (float*)alloc((size_t)NNODE * DDIM * 4);
    int*       row_ptr = (int*)alloc((size_t)(NNODE + 1) * 4);
    int*       deg     = (int*)alloc((size_t)NNODE * 4);       // reused as cnt
    int*       bsums   = (int*)alloc(4096);
    uint2*     edges   = (uint2*)alloc((size_t)E * 8);

    const int NB = (NNODE + 2047) / 2048;   // 71

    zero_ints_kernel<<<(NNODE + 255) / 256, 256, 0, stream>>>(deg, NNODE);
    hist_kernel<<<(E + 255) / 256, 256, 0, stream>>>(rows, deg, E);
    block_sums_kernel<<<NB, 1024, 0, stream>>>(deg, bsums, NNODE);
    scan_bsums_kernel<<<1, 64, 0, stream>>>(bsums, NB);
    block_scan_kernel<<<NB, 1024, 0, stream>>>(deg, bsums, row_ptr, NNODE);
    zero_ints_kernel<<<(NNODE + 255) / 256, 256, 0, stream>>>(deg, NNODE);
    scatter_kernel<<<(E + 255) / 256, 256, 0, stream>>>(rows, cols, vals, row_ptr, deg, edges, E);

    gnn_layer_kernel<1><<<2048, 256, 0, stream>>>(
        embed_user, embed_item, row_ptr, edges, W1, b1, Wi1, bi1, g1);
    gnn_layer_kernel<0><<<2048, 256, 0, stream>>>(
        g1, nullptr, row_ptr, edges, W2, b2, Wi2, bi2, g2);

    init_loss_kernel<<<1, 64, 0, stream>>>(out, 2 * B);
    score_kernel<<<(B * 64 + 255) / 256, 256, 0, stream>>>(
        user, item_i, item_j, embed_user, embed_item, g1, g2, out, B);
}

// Round 4
// 890.891 us; speedup vs baseline: 1.7754x; 1.7754x over previous
//
#include <hip/hip_runtime.h>
#include <hip/hip_bf16.h>
#include <cmath>

#define USER_NUM 52643
#define ITEM_NUM 91599
#define NNODE (USER_NUM + ITEM_NUM)   // 144242
#define DDIM 64

typedef unsigned int uint32;
typedef unsigned short ushort16;

__device__ __forceinline__ ushort16 f2bf(float f) {
    uint32 u = __float_as_uint(f);
    u += 0x7fffu + ((u >> 16) & 1u);   // round-to-nearest-even
    return (ushort16)(u >> 16);
}

// ---------------- small utility kernels ----------------

__global__ void zero_ints_kernel(int* __restrict__ p, int n) {
    int i = blockIdx.x * 256 + threadIdx.x;
    if (i < n) p[i] = 0;
}

__global__ void init_loss_kernel(float* __restrict__ out, int loss_idx) {
    if (threadIdx.x == 0) out[loss_idx] = 0.0f;
}

// ---------------- CSR build ----------------

__global__ void hist_kernel(const int* __restrict__ rows, int* __restrict__ deg, int E) {
    int e = blockIdx.x * 256 + threadIdx.x;
    if (e < E) atomicAdd(&deg[rows[e]], 1);
}

__global__ void block_sums_kernel(const int* __restrict__ deg, int* __restrict__ bsums, int n) {
    int t = threadIdx.x;                 // 1024 threads
    int base = blockIdx.x * 2048;
    int s = 0;
    for (int i = t; i < 2048; i += 1024) {
        int idx = base + i;
        if (idx < n) s += deg[idx];
    }
    for (int off = 32; off; off >>= 1) s += __shfl_xor(s, off);
    __shared__ int ws[16];
    int lane = t & 63, wid = t >> 6;
    if (lane == 0) ws[wid] = s;
    __syncthreads();
    if (t < 64) {
        int v = (t < 16) ? ws[t] : 0;
        for (int off = 32; off; off >>= 1) v += __shfl_xor(v, off);
        if (t == 0) bsums[blockIdx.x] = v;
    }
}

__global__ void scan_bsums_kernel(int* __restrict__ bsums, int nb) {
    if (threadIdx.x == 0 && blockIdx.x == 0) {
        int acc = 0;
        for (int i = 0; i < nb; ++i) { int v = bsums[i]; bsums[i] = acc; acc += v; }
    }
}

__global__ void block_scan_kernel(const int* __restrict__ deg, const int* __restrict__ bsums,
                                  int* __restrict__ row_ptr, int n) {
    int t = threadIdx.x;                  // 1024 threads, 2 elems each
    int lane = t & 63, wid = t >> 6;
    int base = blockIdx.x * 2048;
    int i0 = base + 2 * t, i1 = i0 + 1;
    int d0 = (i0 < n) ? deg[i0] : 0;
    int d1 = (i1 < n) ? deg[i1] : 0;
    int s = d0 + d1;
    int v = s;
    #pragma unroll
    for (int delta = 1; delta < 64; delta <<= 1) {
        int src = lane - delta;
        int tmp = __shfl(v, (src < 0) ? lane : src);
        v += (src < 0) ? 0 : tmp;
    }
    __shared__ int wsum[16];
    __shared__ int woff[16];
    if (lane == 63) wsum[wid] = v;
    __syncthreads();
    if (t < 64) {
        int orig = (t < 16) ? wsum[t] : 0;
        int w = orig;
        #pragma unroll
        for (int delta = 1; delta < 64; delta <<= 1) {
            int src = t - delta;
            int tmp = __shfl(w, (src < 0) ? t : src);
            w += (src < 0) ? 0 : tmp;
        }
        if (t < 16) woff[t] = w - orig;   // exclusive
    }
    __syncthreads();
    int off = bsums[blockIdx.x] + woff[wid];
    int excl = off + v - s;
    if (i0 < n) row_ptr[i0 + 1] = excl + d0;
    if (i1 < n) row_ptr[i1 + 1] = excl + d0 + d1;
    if (blockIdx.x == 0 && t == 0) row_ptr[0] = 0;
}

__global__ void scatter_kernel(const int* __restrict__ rows, const int* __restrict__ cols,
                               const float* __restrict__ vals, const int* __restrict__ row_ptr,
                               int* __restrict__ cnt, uint2* __restrict__ edges, int E) {
    int e = blockIdx.x * 256 + threadIdx.x;
    if (e < E) {
        int r = rows[e];
        int pos = row_ptr[r] + atomicAdd(&cnt[r], 1);
        edges[pos] = make_uint2((uint32)cols[e], __float_as_uint(vals[e]));
    }
}

// ---------------- fused GNN layer ----------------
// EXACT R1 gather-loop structure (per-lane masked edge loads, shuffle broadcast,
// unroll-4, exact grid, no readfirstlane) -- measured 236 MB FETCH / 360 us.
// Only epilogue differs from R1: bf16-packed W in LDS (16.9 KB) + fused bias.

template <int SPLIT>
__global__ __launch_bounds__(256) void gnn_layer_kernel(
    const float* __restrict__ xA, const float* __restrict__ xB,
    const int* __restrict__ row_ptr, const uint2* __restrict__ edges,
    const float* __restrict__ W, const float* __restrict__ b,
    const float* __restrict__ Wi, const float* __restrict__ bi,
    float* __restrict__ out)
{
    __shared__ uint32 Wt2[64 * 65];   // Wt2[k*65+j] = pack(bf16 Wi[j][k] << 16 | bf16 W[j][k])
    __shared__ float bias_s[64];
    int tid = threadIdx.x;
    int lane = tid & 63;
    int wid = tid >> 6;

    for (int i = tid; i < 64 * 64; i += 256) {
        int j = i >> 6, k = i & 63;          // W[j][k]
        Wt2[k * 65 + j] = ((uint32)f2bf(Wi[i]) << 16) | (uint32)f2bf(W[i]);
    }
    if (tid < 64) bias_s[tid] = b[tid] + bi[tid];
    __syncthreads();

    int row = blockIdx.x * 4 + wid;
    if (row >= NNODE) return;

    int e0 = row_ptr[row], e1 = row_ptr[row + 1];
    float acc1 = 0.0f, acc2 = 0.0f;

    for (int base = e0; base < e1; base += 64) {
        int e = base + lane;
        int c = 0; float v = 0.0f;
        if (e < e1) {
            uint2 ed = edges[e];              // per-lane coalesced 8B
            c = (int)ed.x;
            v = __uint_as_float(ed.y);
        }
        int nn = min(64, e1 - base);
        for (int i = 0; i < nn; i += 4) {
            float xv[4], vv[4];
            #pragma unroll
            for (int u = 0; u < 4; ++u) {
                int cc = __shfl(c, i + u);      // tail slots: c=0 -> row 0 (L2-hot), vv=0
                vv[u] = __shfl(v, i + u);
                const float* xp;
                if (SPLIT) xp = (cc < USER_NUM) ? (xA + ((size_t)cc << 6))
                                                : (xB + (((size_t)cc - USER_NUM) << 6));
                else       xp = xA + ((size_t)cc << 6);
                xv[u] = xp[lane];
            }
            #pragma unroll
            for (int u = 0; u < 4; ++u) {
                acc1 = fmaf(vv[u], xv[u], acc1);
                acc2 = fmaf(vv[u], xv[u] * xv[u], acc2);
            }
        }
    }

    float xr;
    if (SPLIT) xr = (row < USER_NUM) ? xA[((size_t)row << 6) + lane]
                                     : xB[(((size_t)row - USER_NUM) << 6) + lane];
    else       xr = xA[((size_t)row << 6) + lane];

    float p1 = acc1 + xr;    // (L + I) @ x
    float p2 = acc2;         // L @ (x*x)

    float oj = bias_s[lane];
    #pragma unroll
    for (int k = 0; k < 64; ++k) {
        float s1 = __shfl(p1, k);
        float s2 = __shfl(p2, k);
        uint32 w2 = Wt2[k * 65 + lane];
        oj = fmaf(s1, __uint_as_float(w2 << 16), oj);
        oj = fmaf(s2, __uint_as_float(w2 & 0xffff0000u), oj);
    }
    oj = fmaxf(oj, 0.0f);
    out[((size_t)row << 6) + lane] = oj;
}

// ---------------- scoring + loss ----------------

__global__ void score_kernel(const int* __restrict__ user, const int* __restrict__ item_i,
                             const int* __restrict__ item_j,
                             const float* __restrict__ eu, const float* __restrict__ ei,
                             const float* __restrict__ g1, const float* __restrict__ g2,
                             float* __restrict__ out, int B)
{
    int t = blockIdx.x * 256 + threadIdx.x;
    int w = t >> 6;
    int lane = t & 63;
    if (w >= B) return;

    int u  = user[w];
    int i0 = item_i[w];
    int j0 = item_j[w];
    int ii = USER_NUM + i0;
    int jj = USER_NUM + j0;

    float e0u = eu[(size_t)u  * DDIM + lane];
    float e0i = ei[(size_t)i0 * DDIM + lane];
    float e0j = ei[(size_t)j0 * DDIM + lane];
    float g1u = g1[(size_t)u  * DDIM + lane];
    float g1i = g1[(size_t)ii * DDIM + lane];
    float g1j = g1[(size_t)jj * DDIM + lane];
    float g2u = g2[(size_t)u  * DDIM + lane];
    float g2i = g2[(size_t)ii * DDIM + lane];
    float g2j = g2[(size_t)jj * DDIM + lane];

    float di = e0u * e0i + g1u * g1i + g2u * g2i;
    float dj = e0u * e0j + g1u * g1j + g2u * g2j;
    for (int off = 32; off; off >>= 1) {
        di += __shfl_xor(di, off);
        dj += __shfl_xor(dj, off);
    }
    if (lane == 0) {
        out[w] = di;
        out[B + w] = dj;
        float x = di - dj;
        float sp = fmaxf(-x, 0.0f) + log1pf(expf(-fabsf(x)));   // softplus(-x)
        atomicAdd(&out[2 * B], sp);
    }
}

// ---------------- launch ----------------

extern "C" void kernel_launch(void* const* d_in, const int* in_sizes, int n_in,
                              void* d_out, int out_size, void* d_ws, size_t ws_size,
                              hipStream_t stream) {
    const int*   user       = (const int*)d_in[0];
    const int*   item_i     = (const int*)d_in[1];
    const int*   item_j     = (const int*)d_in[2];
    const int*   rows       = (const int*)d_in[3];
    const int*   cols       = (const int*)d_in[4];
    const float* vals       = (const float*)d_in[5];
    const float* embed_user = (const float*)d_in[6];
    const float* embed_item = (const float*)d_in[7];
    const float* W1  = (const float*)d_in[8];
    const float* b1  = (const float*)d_in[9];
    const float* Wi1 = (const float*)d_in[10];
    const float* bi1 = (const float*)d_in[11];
    const float* W2  = (const float*)d_in[12];
    const float* b2  = (const float*)d_in[13];
    const float* Wi2 = (const float*)d_in[14];
    const float* bi2 = (const float*)d_in[15];

    int B = in_sizes[0];
    int E = in_sizes[3];
    float* out = (float*)d_out;

    char* ws = (char*)d_ws;
    size_t off = 0;
    auto alloc = [&](size_t bytes) -> void* {
        void* p = ws + off;
        off += (bytes + 255) & ~(size_t)255;
        return p;
    };
    float*     g1      = (float*)alloc((size_t)NNODE * DDIM * 4);
    float*     g2      = (float*)alloc((size_t)NNODE * DDIM * 4);
    int*       row_ptr = (int*)alloc((size_t)(NNODE + 1) * 4);
    int*       deg     = (int*)alloc((size_t)NNODE * 4);       // reused as cnt
    int*       bsums   = (int*)alloc(4096);
    uint2*     edges   = (uint2*)alloc((size_t)E * 8);

    const int NB = (NNODE + 2047) / 2048;   // 71

    zero_ints_kernel<<<(NNODE + 255) / 256, 256, 0, stream>>>(deg, NNODE);
    hist_kernel<<<(E + 255) / 256, 256, 0, stream>>>(rows, deg, E);
    block_sums_kernel<<<NB, 1024, 0, stream>>>(deg, bsums, NNODE);
    scan_bsums_kernel<<<1, 64, 0, stream>>>(bsums, NB);
    block_scan_kernel<<<NB, 1024, 0, stream>>>(deg, bsums, row_ptr, NNODE);
    zero_ints_kernel<<<(NNODE + 255) / 256, 256, 0, stream>>>(deg, NNODE);
    scatter_kernel<<<(E + 255) / 256, 256, 0, stream>>>(rows, cols, vals, row_ptr, deg, edges, E);

    gnn_layer_kernel<1><<<(NNODE + 3) / 4, 256, 0, stream>>>(
        embed_user, embed_item, row_ptr, edges, W1, b1, Wi1, bi1, g1);
    gnn_layer_kernel<0><<<(NNODE + 3) / 4, 256, 0, stream>>>(
        g1, nullptr, row_ptr, edges, W2, b2, Wi2, bi2, g2);

    init_loss_kernel<<<1, 64, 0, stream>>>(out, 2 * B);
    score_kernel<<<(B * 64 + 255) / 256, 256, 0, stream>>>(
        user, item_i, item_j, embed_user, embed_item, g1, g2, out, B);
}

// Round 5
// 549.653 us; speedup vs baseline: 2.8777x; 1.6208x over previous
//
#include <hip/hip_runtime.h>
#include <hip/hip_bf16.h>
#include <cmath>

#define USER_NUM 52643
#define ITEM_NUM 91599
#define NNODE (USER_NUM + ITEM_NUM)   // 144242
#define DDIM 64

typedef unsigned int uint32;
typedef unsigned short ushort16;

using bf16x8 = __attribute__((ext_vector_type(8))) short;
using f32x4  = __attribute__((ext_vector_type(4))) float;

__device__ __forceinline__ ushort16 f2bf(float f) {
    uint32 u = __float_as_uint(f);
    u += 0x7fffu + ((u >> 16) & 1u);   // round-to-nearest-even
    return (ushort16)(u >> 16);
}

// ---------------- small utility kernels ----------------

__global__ void zero_ints_kernel(int* __restrict__ p, int n) {
    int i = blockIdx.x * 256 + threadIdx.x;
    if (i < n) p[i] = 0;
}

__global__ void init_loss_kernel(float* __restrict__ out, int loss_idx) {
    if (threadIdx.x == 0) out[loss_idx] = 0.0f;
}

// ---------------- CSR build ----------------

__global__ void hist_kernel(const int* __restrict__ rows, int* __restrict__ deg, int E) {
    int e = blockIdx.x * 256 + threadIdx.x;
    if (e < E) atomicAdd(&deg[rows[e]], 1);
}

__global__ void block_sums_kernel(const int* __restrict__ deg, int* __restrict__ bsums, int n) {
    int t = threadIdx.x;                 // 1024 threads
    int base = blockIdx.x * 2048;
    int s = 0;
    for (int i = t; i < 2048; i += 1024) {
        int idx = base + i;
        if (idx < n) s += deg[idx];
    }
    for (int off = 32; off; off >>= 1) s += __shfl_xor(s, off);
    __shared__ int ws[16];
    int lane = t & 63, wid = t >> 6;
    if (lane == 0) ws[wid] = s;
    __syncthreads();
    if (t < 64) {
        int v = (t < 16) ? ws[t] : 0;
        for (int off = 32; off; off >>= 1) v += __shfl_xor(v, off);
        if (t == 0) bsums[blockIdx.x] = v;
    }
}

// parallel exclusive scan of <=128 block sums (replaces serial 71-iter loop)
__global__ void scan_bsums_kernel(int* __restrict__ bsums, int nb) {
    __shared__ int s[128];
    int t = threadIdx.x;                 // 128 threads
    int v = (t < nb) ? bsums[t] : 0;
    s[t] = v;
    __syncthreads();
    #pragma unroll
    for (int d = 1; d < 128; d <<= 1) {
        int add = (t >= d) ? s[t - d] : 0;
        __syncthreads();
        s[t] += add;
        __syncthreads();
    }
    if (t < nb) bsums[t] = s[t] - v;     // exclusive
}

__global__ void block_scan_kernel(const int* __restrict__ deg, const int* __restrict__ bsums,
                                  int* __restrict__ row_ptr, int n) {
    int t = threadIdx.x;                  // 1024 threads, 2 elems each
    int lane = t & 63, wid = t >> 6;
    int base = blockIdx.x * 2048;
    int i0 = base + 2 * t, i1 = i0 + 1;
    int d0 = (i0 < n) ? deg[i0] : 0;
    int d1 = (i1 < n) ? deg[i1] : 0;
    int s = d0 + d1;
    int v = s;
    #pragma unroll
    for (int delta = 1; delta < 64; delta <<= 1) {
        int src = lane - delta;
        int tmp = __shfl(v, (src < 0) ? lane : src);
        v += (src < 0) ? 0 : tmp;
    }
    __shared__ int wsum[16];
    __shared__ int woff[16];
    if (lane == 63) wsum[wid] = v;
    __syncthreads();
    if (t < 64) {
        int orig = (t < 16) ? wsum[t] : 0;
        int w = orig;
        #pragma unroll
        for (int delta = 1; delta < 64; delta <<= 1) {
            int src = t - delta;
            int tmp = __shfl(w, (src < 0) ? t : src);
            w += (src < 0) ? 0 : tmp;
        }
        if (t < 16) woff[t] = w - orig;   // exclusive
    }
    __syncthreads();
    int off = bsums[blockIdx.x] + woff[wid];
    int excl = off + v - s;
    if (i0 < n) row_ptr[i0 + 1] = excl + d0;
    if (i1 < n) row_ptr[i1 + 1] = excl + d0 + d1;
    if (blockIdx.x == 0 && t == 0) row_ptr[0] = 0;
}

__global__ void scatter_kernel(const int* __restrict__ rows, const int* __restrict__ cols,
                               const float* __restrict__ vals, const int* __restrict__ row_ptr,
                               int* __restrict__ cnt, uint2* __restrict__ edges, int E) {
    int e = blockIdx.x * 256 + threadIdx.x;
    if (e < E) {
        int r = rows[e];
        int pos = row_ptr[r] + atomicAdd(&cnt[r], 1);
        edges[pos] = make_uint2((uint32)cols[e], __float_as_uint(vals[e]));
    }
}

// ---------------- fused GNN layer with MFMA epilogue ----------------
// Block = 4 waves = 64 rows. Gather phase: R1-exact loop (per-lane masked edge
// loads, shuffle broadcast, unroll-4), 16 rows/wave sequential; p1/p2 -> bf16
// XOR-swizzled LDS tiles [64][64]. MFMA phase: wave w computes out[64][16w..16w+16)
// via 16x mfma_f32_16x16x32_bf16 (A = P rows from LDS, B = W^T rows from global).

template <int SPLIT>
__global__ __launch_bounds__(256, 4) void gnn_layer_kernel(
    const float* __restrict__ xA, const float* __restrict__ xB,
    const int* __restrict__ row_ptr, const uint2* __restrict__ edges,
    const float* __restrict__ W, const float* __restrict__ b,
    const float* __restrict__ Wi, const float* __restrict__ bi,
    float* __restrict__ out)
{
    __shared__ unsigned short P1s[64 * 64];   // [row][dim] bf16, byte-col ^ ((row&7)<<4)
    __shared__ unsigned short P2s[64 * 64];

    int tid = threadIdx.x;
    int lane = tid & 63;
    int wid = tid >> 6;
    int base = blockIdx.x * 64;

    // ---- gather phase: 16 rows per wave ----
    for (int i = 0; i < 16; ++i) {
        int rr = wid * 16 + i;            // row-local 0..63
        int row = base + rr;
        float p1 = 0.0f, p2 = 0.0f;
        if (row < NNODE) {
            int e0 = row_ptr[row], e1 = row_ptr[row + 1];
            float acc1 = 0.0f, acc2 = 0.0f;
            for (int eb = e0; eb < e1; eb += 64) {
                int e = eb + lane;
                int c = 0; float v = 0.0f;
                if (e < e1) {
                    uint2 ed = edges[e];          // per-lane coalesced 8B
                    c = (int)ed.x;
                    v = __uint_as_float(ed.y);
                }
                int nn = min(64, e1 - eb);
                for (int k = 0; k < nn; k += 4) {
                    float xv[4], vv[4];
                    #pragma unroll
                    for (int u = 0; u < 4; ++u) {
                        int cc = __shfl(c, k + u);
                        vv[u] = __shfl(v, k + u);
                        const float* xp;
                        if (SPLIT) xp = (cc < USER_NUM) ? (xA + ((size_t)cc << 6))
                                                        : (xB + (((size_t)cc - USER_NUM) << 6));
                        else       xp = xA + ((size_t)cc << 6);
                        xv[u] = xp[lane];
                    }
                    #pragma unroll
                    for (int u = 0; u < 4; ++u) {
                        acc1 = fmaf(vv[u], xv[u], acc1);
                        acc2 = fmaf(vv[u], xv[u] * xv[u], acc2);
                    }
                }
            }
            float xr;
            if (SPLIT) xr = (row < USER_NUM) ? xA[((size_t)row << 6) + lane]
                                             : xB[(((size_t)row - USER_NUM) << 6) + lane];
            else       xr = xA[((size_t)row << 6) + lane];
            p1 = acc1 + xr;     // (L + I) @ x
            p2 = acc2;          // L @ (x*x)
        }
        // swizzled bf16 LDS write: byte col = 2*lane ^ ((rr&7)<<4)
        int cb = (2 * lane) ^ ((rr & 7) << 4);
        int idx = rr * 64 + (cb >> 1);
        P1s[idx] = (unsigned short)f2bf(p1);
        P2s[idx] = (unsigned short)f2bf(p2);
    }
    __syncthreads();

    // ---- MFMA phase: wave wid computes cols [16*wid, 16*wid+16) for all 64 rows ----
    int l15 = lane & 15;
    int l4  = lane >> 4;
    int n0  = wid * 16;

    // B fragments: lane holds W[n0+l15][kt*32 + l4*8 + j], j=0..7 (= W^T[k][n])
    bf16x8 wf[2], wif[2];
    #pragma unroll
    for (int kt = 0; kt < 2; ++kt) {
        const float* wr  = W  + (size_t)(n0 + l15) * 64 + kt * 32 + l4 * 8;
        const float* wir = Wi + (size_t)(n0 + l15) * 64 + kt * 32 + l4 * 8;
        f32x4 a0 = *(const f32x4*)wr;
        f32x4 a1 = *(const f32x4*)(wr + 4);
        f32x4 c0 = *(const f32x4*)wir;
        f32x4 c1 = *(const f32x4*)(wir + 4);
        bf16x8 t0, t1;
        #pragma unroll
        for (int j = 0; j < 4; ++j) {
            t0[j]     = (short)f2bf(a0[j]);
            t0[j + 4] = (short)f2bf(a1[j]);
            t1[j]     = (short)f2bf(c0[j]);
            t1[j + 4] = (short)f2bf(c1[j]);
        }
        wf[kt]  = t0;
        wif[kt] = t1;
    }
    float bias_v = b[n0 + l15] + bi[n0 + l15];

    f32x4 acc0 = {0.f,0.f,0.f,0.f}, acc1v = {0.f,0.f,0.f,0.f};
    f32x4 acc2v = {0.f,0.f,0.f,0.f}, acc3 = {0.f,0.f,0.f,0.f};
    f32x4* accp[4] = {&acc0, &acc1v, &acc2v, &acc3};

    #pragma unroll
    for (int mt = 0; mt < 4; ++mt) {
        #pragma unroll
        for (int kt = 0; kt < 2; ++kt) {
            int rl = mt * 16 + l15;
            int cb = (kt * 64 + l4 * 16) ^ ((rl & 7) << 4);
            int idx = rl * 64 + (cb >> 1);
            bf16x8 a1f = *(const bf16x8*)&P1s[idx];
            bf16x8 a2f = *(const bf16x8*)&P2s[idx];
            *accp[mt] = __builtin_amdgcn_mfma_f32_16x16x32_bf16(a1f, wf[kt],  *accp[mt], 0, 0, 0);
            *accp[mt] = __builtin_amdgcn_mfma_f32_16x16x32_bf16(a2f, wif[kt], *accp[mt], 0, 0, 0);
        }
    }

    // C layout: col = lane&15, row = (lane>>4)*4 + j  (+ mt*16)
    #pragma unroll
    for (int mt = 0; mt < 4; ++mt) {
        #pragma unroll
        for (int j = 0; j < 4; ++j) {
            int r = base + mt * 16 + l4 * 4 + j;
            if (r < NNODE) {
                float o = fmaxf((*accp[mt])[j] + bias_v, 0.0f);
                out[(size_t)r * 64 + n0 + l15] = o;
            }
        }
    }
}

// ---------------- scoring + loss ----------------

__global__ void score_kernel(const int* __restrict__ user, const int* __restrict__ item_i,
                             const int* __restrict__ item_j,
                             const float* __restrict__ eu, const float* __restrict__ ei,
                             const float* __restrict__ g1, const float* __restrict__ g2,
                             float* __restrict__ out, int B)
{
    int t = blockIdx.x * 256 + threadIdx.x;
    int w = t >> 6;
    int lane = t & 63;
    if (w >= B) return;

    int u  = user[w];
    int i0 = item_i[w];
    int j0 = item_j[w];
    int ii = USER_NUM + i0;
    int jj = USER_NUM + j0;

    float e0u = eu[(size_t)u  * DDIM + lane];
    float e0i = ei[(size_t)i0 * DDIM + lane];
    float e0j = ei[(size_t)j0 * DDIM + lane];
    float g1u = g1[(size_t)u  * DDIM + lane];
    float g1i = g1[(size_t)ii * DDIM + lane];
    float g1j = g1[(size_t)jj * DDIM + lane];
    float g2u = g2[(size_t)u  * DDIM + lane];
    float g2i = g2[(size_t)ii * DDIM + lane];
    float g2j = g2[(size_t)jj * DDIM + lane];

    float di = e0u * e0i + g1u * g1i + g2u * g2i;
    float dj = e0u * e0j + g1u * g1j + g2u * g2j;
    for (int off = 32; off; off >>= 1) {
        di += __shfl_xor(di, off);
        dj += __shfl_xor(dj, off);
    }
    if (lane == 0) {
        out[w] = di;
        out[B + w] = dj;
        float x = di - dj;
        float sp = fmaxf(-x, 0.0f) + log1pf(expf(-fabsf(x)));   // softplus(-x)
        atomicAdd(&out[2 * B], sp);
    }
}

// ---------------- launch ----------------

extern "C" void kernel_launch(void* const* d_in, const int* in_sizes, int n_in,
                              void* d_out, int out_size, void* d_ws, size_t ws_size,
                              hipStream_t stream) {
    const int*   user       = (const int*)d_in[0];
    const int*   item_i     = (const int*)d_in[1];
    const int*   item_j     = (const int*)d_in[2];
    const int*   rows       = (const int*)d_in[3];
    const int*   cols       = (const int*)d_in[4];
    const float* vals       = (const float*)d_in[5];
    const float* embed_user = (const float*)d_in[6];
    const float* embed_item = (const float*)d_in[7];
    const float* W1  = (const float*)d_in[8];
    const float* b1  = (const float*)d_in[9];
    const float* Wi1 = (const float*)d_in[10];
    const float* bi1 = (const float*)d_in[11];
    const float* W2  = (const float*)d_in[12];
    const float* b2  = (const float*)d_in[13];
    const float* Wi2 = (const float*)d_in[14];
    const float* bi2 = (const float*)d_in[15];

    int B = in_sizes[0];
    int E = in_sizes[3];
    float* out = (float*)d_out;

    char* ws = (char*)d_ws;
    size_t off = 0;
    auto alloc = [&](size_t bytes) -> void* {
        void* p = ws + off;
        off += (bytes + 255) & ~(size_t)255;
        return p;
    };
    float*     g1      = (float*)alloc((size_t)NNODE * DDIM * 4);
    float*     g2      = (float*)alloc((size_t)NNODE * DDIM * 4);
    int*       row_ptr = (int*)alloc((size_t)(NNODE + 1) * 4);
    int*       deg     = (int*)alloc((size_t)NNODE * 4);       // reused as cnt
    int*       bsums   = (int*)alloc(4096);
    uint2*     edges   = (uint2*)alloc((size_t)E * 8);

    const int NB = (NNODE + 2047) / 2048;   // 71

    zero_ints_kernel<<<(NNODE + 255) / 256, 256, 0, stream>>>(deg, NNODE);
    hist_kernel<<<(E + 255) / 256, 256, 0, stream>>>(rows, deg, E);
    block_sums_kernel<<<NB, 1024, 0, stream>>>(deg, bsums, NNODE);
    scan_bsums_kernel<<<1, 128, 0, stream>>>(bsums, NB);
    block_scan_kernel<<<NB, 1024, 0, stream>>>(deg, bsums, row_ptr, NNODE);
    zero_ints_kernel<<<(NNODE + 255) / 256, 256, 0, stream>>>(deg, NNODE);
    scatter_kernel<<<(E + 255) / 256, 256, 0, stream>>>(rows, cols, vals, row_ptr, deg, edges, E);

    const int GNNB = (NNODE + 63) / 64;   // 2254
    gnn_layer_kernel<1><<<GNNB, 256, 0, stream>>>(
        embed_user, embed_item, row_ptr, edges, W1, b1, Wi1, bi1, g1);
    gnn_layer_kernel<0><<<GNNB, 256, 0, stream>>>(
        g1, nullptr, row_ptr, edges, W2, b2, Wi2, bi2, g2);

    init_loss_kernel<<<1, 64, 0, stream>>>(out, 2 * B);
    score_kernel<<<(B * 64 + 255) / 256, 256, 0, stream>>>(
        user, item_i, item_j, embed_user, embed_item, g1, g2, out, B);
}

// Round 6
// 523.113 us; speedup vs baseline: 3.0237x; 1.0507x over previous
//
#include <hip/hip_runtime.h>
#include <hip/hip_bf16.h>
#include <cmath>

#define USER_NUM 52643
#define ITEM_NUM 91599
#define NNODE (USER_NUM + ITEM_NUM)   // 144242
#define DDIM 64

typedef unsigned int uint32;

using bf16x8 = __attribute__((ext_vector_type(8))) short;
using f32x4  = __attribute__((ext_vector_type(4))) float;

__device__ __forceinline__ uint32 f2bf(float f) {
    uint32 u = __float_as_uint(f);
    u += 0x7fffu + ((u >> 16) & 1u);   // round-to-nearest-even
    return u >> 16;
}
__device__ __forceinline__ uint32 packbf(float lo, float hi) {
    return (f2bf(hi) << 16) | f2bf(lo);
}

// ---------------- small utility kernels ----------------

__global__ void zero_ints_kernel(int* __restrict__ p, int n) {
    int i = blockIdx.x * 256 + threadIdx.x;
    if (i < n) p[i] = 0;
}

__global__ void init_loss_kernel(float* __restrict__ out, int loss_idx) {
    if (threadIdx.x == 0) out[loss_idx] = 0.0f;
}

// ---------------- CSR build ----------------

__global__ void hist_kernel(const int* __restrict__ rows, int* __restrict__ deg, int E) {
    int e = blockIdx.x * 256 + threadIdx.x;
    if (e < E) atomicAdd(&deg[rows[e]], 1);
}

// dinv = deg^-1/2 (0 if deg==0); wout = epilogue scale; sback = inverse scale
__global__ void dinv_kernel(const int* __restrict__ deg, float* __restrict__ dinv,
                            float* __restrict__ wout, float* __restrict__ sback) {
    int n = blockIdx.x * 256 + threadIdx.x;
    if (n >= NNODE) return;
    int d = deg[n];
    float df = (float)d;
    float dv = (d > 0) ? (1.0f / sqrtf(df)) : 0.0f;
    dinv[n]  = dv;
    wout[n]  = (d > 0) ? dv : 1.0f;
    sback[n] = (d > 0) ? sqrtf(df) : 1.0f;
}

__global__ void block_sums_kernel(const int* __restrict__ deg, int* __restrict__ bsums, int n) {
    int t = threadIdx.x;                 // 1024 threads
    int base = blockIdx.x * 2048;
    int s = 0;
    for (int i = t; i < 2048; i += 1024) {
        int idx = base + i;
        if (idx < n) s += deg[idx];
    }
    for (int off = 32; off; off >>= 1) s += __shfl_xor(s, off);
    __shared__ int ws[16];
    int lane = t & 63, wid = t >> 6;
    if (lane == 0) ws[wid] = s;
    __syncthreads();
    if (t < 64) {
        int v = (t < 16) ? ws[t] : 0;
        for (int off = 32; off; off >>= 1) v += __shfl_xor(v, off);
        if (t == 0) bsums[blockIdx.x] = v;
    }
}

__global__ void scan_bsums_kernel(int* __restrict__ bsums, int nb) {
    __shared__ int s[128];
    int t = threadIdx.x;                 // 128 threads
    int v = (t < nb) ? bsums[t] : 0;
    s[t] = v;
    __syncthreads();
    #pragma unroll
    for (int d = 1; d < 128; d <<= 1) {
        int add = (t >= d) ? s[t - d] : 0;
        __syncthreads();
        s[t] += add;
        __syncthreads();
    }
    if (t < nb) bsums[t] = s[t] - v;     // exclusive
}

__global__ void block_scan_kernel(const int* __restrict__ deg, const int* __restrict__ bsums,
                                  int* __restrict__ row_ptr, int n) {
    int t = threadIdx.x;                  // 1024 threads, 2 elems each
    int lane = t & 63, wid = t >> 6;
    int base = blockIdx.x * 2048;
    int i0 = base + 2 * t, i1 = i0 + 1;
    int d0 = (i0 < n) ? deg[i0] : 0;
    int d1 = (i1 < n) ? deg[i1] : 0;
    int s = d0 + d1;
    int v = s;
    #pragma unroll
    for (int delta = 1; delta < 64; delta <<= 1) {
        int src = lane - delta;
        int tmp = __shfl(v, (src < 0) ? lane : src);
        v += (src < 0) ? 0 : tmp;
    }
    __shared__ int wsum[16];
    __shared__ int woff[16];
    if (lane == 63) wsum[wid] = v;
    __syncthreads();
    if (t < 64) {
        int orig = (t < 16) ? wsum[t] : 0;
        int w = orig;
        #pragma unroll
        for (int delta = 1; delta < 64; delta <<= 1) {
            int src = t - delta;
            int tmp = __shfl(w, (src < 0) ? t : src);
            w += (src < 0) ? 0 : tmp;
        }
        if (t < 16) woff[t] = w - orig;   // exclusive
    }
    __syncthreads();
    int off = bsums[blockIdx.x] + woff[wid];
    int excl = off + v - s;
    if (i0 < n) row_ptr[i0 + 1] = excl + d0;
    if (i1 < n) row_ptr[i1 + 1] = excl + d0 + d1;
    if (blockIdx.x == 0 && t == 0) row_ptr[0] = 0;
}

// scatter: 4B per edge (col only)
__global__ void scatter_kernel(const int* __restrict__ rows, const int* __restrict__ cols,
                               const int* __restrict__ row_ptr,
                               int* __restrict__ cnt, int* __restrict__ csr_col, int E) {
    int e = blockIdx.x * 256 + threadIdx.x;
    if (e < E) {
        int r = rows[e];
        int pos = row_ptr[r] + atomicAdd(&cnt[r], 1);
        csr_col[pos] = cols[e];
    }
}

// pack layer-1 gather table: y1b[n][d2] = bf16pair(dinv*x[2d2], dinv*x[2d2+1]); also zero dummy rows
__global__ void pack1_kernel(const float* __restrict__ eu, const float* __restrict__ ei,
                             const float* __restrict__ dinv,
                             uint32* __restrict__ y1b, uint32* __restrict__ y1b2,
                             uint32* __restrict__ y2b) {
    int t = blockIdx.x * 256 + threadIdx.x;     // t = n*32 + d2
    int n = t >> 5, d2 = t & 31;
    if (n > NNODE) return;
    if (n == NNODE) { y1b[t] = 0; y1b2[t] = 0; y2b[t] = 0; return; }
    const float* xp = (n < USER_NUM) ? (eu + ((size_t)n << 6))
                                     : (ei + (((size_t)n - USER_NUM) << 6));
    float2 x2 = *(const float2*)(xp + 2 * d2);
    float dv = dinv[n];
    y1b[t] = packbf(dv * x2.x, dv * x2.y);
}

// ---------------- fused GNN layer ----------------
// Gather: pair-mode — lane l handles dim-pair (l&31) of edge parity (l>>5);
// one 4B bf16-pair gather per edge covers both y1-dims; p2 via y^2*sback_c.
// Tail lanes use dummy row NNODE (zeros). Epilogue: MFMA, writes packed table.

template <int SPLIT>
__global__ __launch_bounds__(256, 4) void gnn_layer_kernel(
    const uint32* __restrict__ ytab,
    const float* __restrict__ eA, const float* __restrict__ eB,
    const int* __restrict__ row_ptr, const int* __restrict__ csr_col,
    const float* __restrict__ sback, const float* __restrict__ dinv,
    const float* __restrict__ wout,
    const float* __restrict__ W, const float* __restrict__ b,
    const float* __restrict__ Wi, const float* __restrict__ bi,
    uint32* __restrict__ otab)
{
    __shared__ unsigned short P1s[64 * 64];   // [row][dim] bf16, byte-col ^ ((row&7)<<4)
    __shared__ unsigned short P2s[64 * 64];

    int tid = threadIdx.x;
    int lane = tid & 63;
    int wid = tid >> 6;
    int h = lane >> 5;        // edge parity
    int d2 = lane & 31;       // dim-pair index
    int base = blockIdx.x * 64;

    // ---- gather phase: 16 rows per wave ----
    for (int i = 0; i < 16; ++i) {
        int rr = wid * 16 + i;            // row-local 0..63
        int row = base + rr;
        float p1l = 0.f, p1h = 0.f, p2l = 0.f, p2h = 0.f;
        if (row < NNODE) {
            int e0 = row_ptr[row], e1 = row_ptr[row + 1];
            float aA = 0.f, aB = 0.f, aC = 0.f, aD = 0.f;
            for (int eb = e0; eb < e1; eb += 64) {
                int e = eb + lane;
                int c = NNODE; float si = 0.f;
                if (e < e1) {
                    c = csr_col[e];         // coalesced 4B
                    si = sback[c];          // hot 576KB table
                }
                int nn = min(64, e1 - eb);
                for (int k = 0; k < nn; k += 8) {
                    #pragma unroll
                    for (int u = 0; u < 4; ++u) {
                        int idx = k + 2 * u + h;          // <=63; idx>=nn lanes hold dummy
                        int cc = __shfl(c, idx);
                        float ii = __shfl(si, idx);
                        uint32 w = ytab[(size_t)cc * 32 + d2];   // 4B bf16-pair gather
                        float f0 = __uint_as_float(w << 16);
                        float f1 = __uint_as_float(w & 0xffff0000u);
                        aA += f0; aB += f1;
                        aC = fmaf(f0 * f0, ii, aC);
                        aD = fmaf(f1 * f1, ii, aD);
                    }
                }
            }
            // combine edge parities
            aA += __shfl_xor(aA, 32); aB += __shfl_xor(aB, 32);
            aC += __shfl_xor(aC, 32); aD += __shfl_xor(aD, 32);
            float dv = dinv[row];
            float xl, xh;
            if (SPLIT) {
                const float* xp = (row < USER_NUM) ? (eA + ((size_t)row << 6))
                                                   : (eB + (((size_t)row - USER_NUM) << 6));
                float2 x2 = *(const float2*)(xp + 2 * d2);
                xl = x2.x; xh = x2.y;
            } else {
                uint32 w = ytab[(size_t)row * 32 + d2];
                float s = sback[row];
                xl = __uint_as_float(w << 16) * s;
                xh = __uint_as_float(w & 0xffff0000u) * s;
            }
            p1l = fmaf(dv, aA, xl);   // (L+I)@x
            p1h = fmaf(dv, aB, xh);
            p2l = dv * aC;            // L@(x*x)
            p2h = dv * aD;
        }
        if (h == 0) {
            int cb = (4 * d2) ^ ((rr & 7) << 4);
            *(uint32*)&P1s[rr * 64 + (cb >> 1)] = packbf(p1l, p1h);
            *(uint32*)&P2s[rr * 64 + (cb >> 1)] = packbf(p2l, p2h);
        }
    }
    __syncthreads();

    // ---- MFMA phase: wave wid computes cols [16*wid, 16*wid+16) for all 64 rows ----
    int l15 = lane & 15;
    int l4  = lane >> 4;
    int n0  = wid * 16;

    bf16x8 wf[2], wif[2];
    #pragma unroll
    for (int kt = 0; kt < 2; ++kt) {
        const float* wr  = W  + (size_t)(n0 + l15) * 64 + kt * 32 + l4 * 8;
        const float* wir = Wi + (size_t)(n0 + l15) * 64 + kt * 32 + l4 * 8;
        f32x4 a0 = *(const f32x4*)wr;
        f32x4 a1 = *(const f32x4*)(wr + 4);
        f32x4 c0 = *(const f32x4*)wir;
        f32x4 c1 = *(const f32x4*)(wir + 4);
        bf16x8 t0, t1;
        #pragma unroll
        for (int j = 0; j < 4; ++j) {
            t0[j]     = (short)f2bf(a0[j]);
            t0[j + 4] = (short)f2bf(a1[j]);
            t1[j]     = (short)f2bf(c0[j]);
            t1[j + 4] = (short)f2bf(c1[j]);
        }
        wf[kt]  = t0;
        wif[kt] = t1;
    }
    float bias_v = b[n0 + l15] + bi[n0 + l15];

    f32x4 acc0 = {0.f,0.f,0.f,0.f}, acc1v = {0.f,0.f,0.f,0.f};
    f32x4 acc2v = {0.f,0.f,0.f,0.f}, acc3 = {0.f,0.f,0.f,0.f};
    f32x4* accp[4] = {&acc0, &acc1v, &acc2v, &acc3};

    #pragma unroll
    for (int mt = 0; mt < 4; ++mt) {
        #pragma unroll
        for (int kt = 0; kt < 2; ++kt) {
            int rl = mt * 16 + l15;
            int cb = (kt * 64 + l4 * 16) ^ ((rl & 7) << 4);
            int idx = rl * 64 + (cb >> 1);
            bf16x8 a1f = *(const bf16x8*)&P1s[idx];
            bf16x8 a2f = *(const bf16x8*)&P2s[idx];
            *accp[mt] = __builtin_amdgcn_mfma_f32_16x16x32_bf16(a1f, wf[kt],  *accp[mt], 0, 0, 0);
            *accp[mt] = __builtin_amdgcn_mfma_f32_16x16x32_bf16(a2f, wif[kt], *accp[mt], 0, 0, 0);
        }
    }

    // C layout: col = lane&15, row = (lane>>4)*4 + j (+ mt*16). Write packed table.
    #pragma unroll
    for (int mt = 0; mt < 4; ++mt) {
        #pragma unroll
        for (int j = 0; j < 4; ++j) {
            int r = base + mt * 16 + l4 * 4 + j;
            float o = fmaxf((*accp[mt])[j] + bias_v, 0.0f);
            float wsc = (r < NNODE) ? wout[r] : 0.0f;
            o *= wsc;
            float onb = __shfl_xor(o, 1);
            if (((l15 & 1) == 0) && r < NNODE)
                otab[(size_t)r * 32 + ((n0 + l15) >> 1)] = packbf(o, onb);
        }
    }
}

// ---------------- scoring + loss ----------------

__global__ void score_kernel(const int* __restrict__ user, const int* __restrict__ item_i,
                             const int* __restrict__ item_j,
                             const float* __restrict__ eu, const float* __restrict__ ei,
                             const uint32* __restrict__ y1b2, const uint32* __restrict__ y2b,
                             const float* __restrict__ sback,
                             float* __restrict__ out, int B)
{
    int t = blockIdx.x * 256 + threadIdx.x;
    int w = t >> 6;
    int lane = t & 63;
    if (w >= B) return;

    int u  = user[w];
    int i0 = item_i[w];
    int j0 = item_j[w];
    int ii = USER_NUM + i0;
    int jj = USER_NUM + j0;

    // embed0 part: lane = dim
    float e0u = eu[(size_t)u  * DDIM + lane];
    float e0i = ei[(size_t)i0 * DDIM + lane];
    float e0j = ei[(size_t)j0 * DDIM + lane];
    float di = e0u * e0i;
    float dj = e0u * e0j;

    // g1/g2 parts: half-waves pick table; lane handles a dim-pair
    int h = lane >> 5, d2 = lane & 31;
    const uint32* tb = h ? y2b : y1b2;
    float su = sback[u], si2 = sback[ii], sj2 = sback[jj];
    uint32 wu = tb[(size_t)u  * 32 + d2];
    uint32 wi = tb[(size_t)ii * 32 + d2];
    uint32 wj = tb[(size_t)jj * 32 + d2];
    float u0 = __uint_as_float(wu << 16) * su,         u1 = __uint_as_float(wu & 0xffff0000u) * su;
    float i0f = __uint_as_float(wi << 16) * si2,       i1f = __uint_as_float(wi & 0xffff0000u) * si2;
    float j0f = __uint_as_float(wj << 16) * sj2,       j1f = __uint_as_float(wj & 0xffff0000u) * sj2;
    di += u0 * i0f + u1 * i1f;
    dj += u0 * j0f + u1 * j1f;

    for (int off = 32; off; off >>= 1) {
        di += __shfl_xor(di, off);
        dj += __shfl_xor(dj, off);
    }
    if (lane == 0) {
        out[w] = di;
        out[B + w] = dj;
        float x = di - dj;
        float sp = fmaxf(-x, 0.0f) + log1pf(expf(-fabsf(x)));   // softplus(-x)
        atomicAdd(&out[2 * B], sp);
    }
}

// ---------------- launch ----------------

extern "C" void kernel_launch(void* const* d_in, const int* in_sizes, int n_in,
                              void* d_out, int out_size, void* d_ws, size_t ws_size,
                              hipStream_t stream) {
    const int*   user       = (const int*)d_in[0];
    const int*   item_i     = (const int*)d_in[1];
    const int*   item_j     = (const int*)d_in[2];
    const int*   rows       = (const int*)d_in[3];
    const int*   cols       = (const int*)d_in[4];
    const float* embed_user = (const float*)d_in[6];
    const float* embed_item = (const float*)d_in[7];
    const float* W1  = (const float*)d_in[8];
    const float* b1  = (const float*)d_in[9];
    const float* Wi1 = (const float*)d_in[10];
    const float* bi1 = (const float*)d_in[11];
    const float* W2  = (const float*)d_in[12];
    const float* b2  = (const float*)d_in[13];
    const float* Wi2 = (const float*)d_in[14];
    const float* bi2 = (const float*)d_in[15];

    int B = in_sizes[0];
    int E = in_sizes[3];
    float* out = (float*)d_out;

    char* ws = (char*)d_ws;
    size_t off = 0;
    auto alloc = [&](size_t bytes) -> void* {
        void* p = ws + off;
        off += (bytes + 255) & ~(size_t)255;
        return p;
    };
    uint32* y1b     = (uint32*)alloc((size_t)(NNODE + 1) * 32 * 4);
    uint32* y1b2    = (uint32*)alloc((size_t)(NNODE + 1) * 32 * 4);
    uint32* y2b     = (uint32*)alloc((size_t)(NNODE + 1) * 32 * 4);
    int*    row_ptr = (int*)alloc((size_t)(NNODE + 1) * 4);
    int*    deg     = (int*)alloc((size_t)NNODE * 4);       // reused as cnt
    int*    bsums   = (int*)alloc(4096);
    int*    csr_col = (int*)alloc((size_t)E * 4);
    float*  dinv    = (float*)alloc((size_t)NNODE * 4);
    float*  wout    = (float*)alloc((size_t)NNODE * 4);
    float*  sback   = (float*)alloc((size_t)NNODE * 4);

    const int NB = (NNODE + 2047) / 2048;   // 71

    zero_ints_kernel<<<(NNODE + 255) / 256, 256, 0, stream>>>(deg, NNODE);
    hist_kernel<<<(E + 255) / 256, 256, 0, stream>>>(rows, deg, E);
    dinv_kernel<<<(NNODE + 255) / 256, 256, 0, stream>>>(deg, dinv, wout, sback);
    block_sums_kernel<<<NB, 1024, 0, stream>>>(deg, bsums, NNODE);
    scan_bsums_kernel<<<1, 128, 0, stream>>>(bsums, NB);
    block_scan_kernel<<<NB, 1024, 0, stream>>>(deg, bsums, row_ptr, NNODE);
    zero_ints_kernel<<<(NNODE + 255) / 256, 256, 0, stream>>>(deg, NNODE);
    scatter_kernel<<<(E + 255) / 256, 256, 0, stream>>>(rows, cols, row_ptr, deg, csr_col, E);

    pack1_kernel<<<((NNODE + 1) * 32 + 255) / 256, 256, 0, stream>>>(
        embed_user, embed_item, dinv, y1b, y1b2, y2b);

    const int GNNB = (NNODE + 63) / 64;   // 2254
    gnn_layer_kernel<1><<<GNNB, 256, 0, stream>>>(
        y1b, embed_user, embed_item, row_ptr, csr_col, sback, dinv, wout,
        W1, b1, Wi1, bi1, y1b2);
    gnn_layer_kernel<0><<<GNNB, 256, 0, stream>>>(
        y1b2, nullptr, nullptr, row_ptr, csr_col, sback, dinv, wout,
        W2, b2, Wi2, bi2, y2b);

    init_loss_kernel<<<1, 64, 0, stream>>>(out, 2 * B);
    score_kernel<<<(B * 64 + 255) / 256, 256, 0, stream>>>(
        user, item_i, item_j, embed_user, embed_item, y1b2, y2b, sback, out, B);
}

// Round 7
// 334.909 us; speedup vs baseline: 4.7228x; 1.5620x over previous
//
#include <hip/hip_runtime.h>
#include <hip/hip_bf16.h>
#include <cmath>

#define USER_NUM 52643
#define ITEM_NUM 91599
#define NNODE (USER_NUM + ITEM_NUM)   // 144242
#define DDIM 64
#define NBUCK 564                     // ceil(NNODE/256)
#define EPB 8192                      // edges per staging block
#define BCAP 8192                     // max edges per bucket (mean ~4.9K, 47-sigma margin)

typedef unsigned int uint32;

using bf16x8 = __attribute__((ext_vector_type(8))) short;
using f32x4  = __attribute__((ext_vector_type(4))) float;

__device__ __forceinline__ uint32 f2bf(float f) {
    uint32 u = __float_as_uint(f);
    u += 0x7fffu + ((u >> 16) & 1u);   // round-to-nearest-even
    return u >> 16;
}
__device__ __forceinline__ uint32 packbf(float lo, float hi) {
    return (f2bf(hi) << 16) | f2bf(lo);
}

// ---------------- small utility kernels ----------------

__global__ void init_loss_kernel(float* __restrict__ out, int loss_idx) {
    if (threadIdx.x == 0) out[loss_idx] = 0.0f;
}

// ---------------- bucketed CSR build (all global writes dense) ----------------

// K2: per-block bucket histogram -> blkcnt[block][NBUCK]
__global__ __launch_bounds__(1024) void bucket_count_kernel(
    const int* __restrict__ rows, int* __restrict__ blkcnt, int E)
{
    __shared__ int cnt[NBUCK];
    int t = threadIdx.x;
    for (int i = t; i < NBUCK; i += 1024) cnt[i] = 0;
    __syncthreads();
    int base = blockIdx.x * EPB;
    for (int i = t; i < EPB; i += 1024) {
        int e = base + i;
        if (e < E) atomicAdd(&cnt[rows[e] >> 8], 1);
    }
    __syncthreads();
    for (int i = t; i < NBUCK; i += 1024) blkcnt[blockIdx.x * NBUCK + i] = cnt[i];
}

// K3: one block per bucket; exclusive scan of blkcnt over blocks; totals[b]
__global__ __launch_bounds__(256) void bucket_block_scan_kernel(
    int* __restrict__ blkcnt, int* __restrict__ totals, int nblocks)
{
    __shared__ int wsum[4];
    int b = blockIdx.x, t = threadIdx.x;
    int lane = t & 63, wid = t >> 6;
    int c = (t < nblocks) ? blkcnt[t * NBUCK + b] : 0;
    int v = c;
    #pragma unroll
    for (int d = 1; d < 64; d <<= 1) {
        int src = (lane >= d) ? (lane - d) : lane;
        int tmp = __shfl(v, src);
        v += (lane >= d) ? tmp : 0;
    }
    if (lane == 63) wsum[wid] = v;
    __syncthreads();
    int woff = 0;
    for (int w = 0; w < wid; ++w) woff += wsum[w];
    int excl = woff + v - c;
    if (t < nblocks) blkcnt[t * NBUCK + b] = excl;
    if (t == 255) totals[b] = excl + c;
}

// K4: exclusive scan of totals -> bucket_off (= row_ptr at bucket starts)
__global__ __launch_bounds__(1024) void bucket_off_kernel(
    const int* __restrict__ totals, int* __restrict__ bucket_off,
    int* __restrict__ row_ptr, int E)
{
    __shared__ int s[1024];
    int t = threadIdx.x;
    int v = (t < NBUCK) ? totals[t] : 0;
    s[t] = v;
    __syncthreads();
    #pragma unroll
    for (int d = 1; d < 1024; d <<= 1) {
        int add = (t >= d) ? s[t - d] : 0;
        __syncthreads();
        s[t] += add;
        __syncthreads();
    }
    if (t < NBUCK) bucket_off[t] = s[t] - v;
    if (t == 0) { bucket_off[NBUCK] = E; row_ptr[NNODE] = E; }
}

// K5: stage edges into bucket slices, packed (r&255)<<18 | col (dense-ish writes)
__global__ __launch_bounds__(1024) void stage_kernel(
    const int* __restrict__ rows, const int* __restrict__ cols,
    const int* __restrict__ blkcnt, const int* __restrict__ bucket_off,
    uint32* __restrict__ staged, int E)
{
    __shared__ int cnt[NBUCK];
    __shared__ int basel[NBUCK];
    int t = threadIdx.x;
    for (int i = t; i < NBUCK; i += 1024) {
        cnt[i] = 0;
        basel[i] = bucket_off[i] + blkcnt[blockIdx.x * NBUCK + i];
    }
    __syncthreads();
    int base = blockIdx.x * EPB;
    for (int i = t; i < EPB; i += 1024) {
        int e = base + i;
        if (e < E) {
            int r = rows[e];
            int bkt = r >> 8;
            int rank = atomicAdd(&cnt[bkt], 1);
            staged[basel[bkt] + rank] = ((uint32)(r & 255) << 18) | (uint32)cols[e];
        }
    }
}

// K6: one block per bucket: derive degrees (-> row_ptr, dinv, wout, sback),
// LDS-order the cols, stream out csr_col densely.
__global__ __launch_bounds__(256) void build_kernel(
    const uint32* __restrict__ staged, const int* __restrict__ bucket_off,
    int* __restrict__ row_ptr, int* __restrict__ csr_col,
    float* __restrict__ dinv, float* __restrict__ wout, float* __restrict__ sback)
{
    __shared__ int cnt[256];
    __shared__ int off[256];
    __shared__ int wsum[4];
    __shared__ int colbuf[BCAP];
    int b = blockIdx.x, t = threadIdx.x;
    int lane = t & 63, wid = t >> 6;
    int eoff = bucket_off[b];
    int ecnt = bucket_off[b + 1] - eoff;

    cnt[t] = 0;
    __syncthreads();
    for (int i = t; i < ecnt; i += 256) atomicAdd(&cnt[staged[eoff + i] >> 18], 1);
    __syncthreads();

    int c = cnt[t];
    int v = c;
    #pragma unroll
    for (int d = 1; d < 64; d <<= 1) {
        int src = (lane >= d) ? (lane - d) : lane;
        int tmp = __shfl(v, src);
        v += (lane >= d) ? tmp : 0;
    }
    if (lane == 63) wsum[wid] = v;
    __syncthreads();
    int woff = 0;
    for (int w = 0; w < wid; ++w) woff += wsum[w];
    int excl = woff + v - c;
    off[t] = excl;

    int node = b * 256 + t;
    if (node < NNODE) {
        row_ptr[node] = eoff + excl;
        float df = (float)c;
        float dv = (c > 0) ? (1.0f / sqrtf(df)) : 0.0f;
        dinv[node]  = dv;
        wout[node]  = (c > 0) ? dv : 1.0f;
        sback[node] = (c > 0) ? sqrtf(df) : 1.0f;
    }
    __syncthreads();
    cnt[t] = 0;
    __syncthreads();
    for (int i = t; i < ecnt; i += 256) {
        uint32 w = staged[eoff + i];
        int rl = w >> 18;
        int rank = atomicAdd(&cnt[rl], 1);
        colbuf[off[rl] + rank] = (int)(w & 0x3FFFFu);
    }
    __syncthreads();
    for (int i = t; i < ecnt; i += 256) csr_col[eoff + i] = colbuf[i];
}

// pack layer-1 gather table: y1b[n][d2] = bf16pair(dinv*x[2d2], dinv*x[2d2+1]); zero dummy row
__global__ void pack1_kernel(const float* __restrict__ eu, const float* __restrict__ ei,
                             const float* __restrict__ dinv,
                             uint32* __restrict__ y1b, uint32* __restrict__ y1b2,
                             uint32* __restrict__ y2b) {
    int t = blockIdx.x * 256 + threadIdx.x;     // t = n*32 + d2
    int n = t >> 5, d2 = t & 31;
    if (n > NNODE) return;
    if (n == NNODE) { y1b[t] = 0; y1b2[t] = 0; y2b[t] = 0; return; }
    const float* xp = (n < USER_NUM) ? (eu + ((size_t)n << 6))
                                     : (ei + (((size_t)n - USER_NUM) << 6));
    float2 x2 = *(const float2*)(xp + 2 * d2);
    float dv = dinv[n];
    y1b[t] = packbf(dv * x2.x, dv * x2.y);
    (void)d2;
}

// ---------------- fused GNN layer ----------------
// Gather: pair-mode — lane l handles dim-pair (l&31) of edge parity (l>>5);
// one 4B bf16-pair gather per edge covers both y1-dims; p2 via y^2*sback_c.
// Tail lanes use dummy row NNODE (zeros). Epilogue: MFMA, writes packed table.

template <int SPLIT>
__global__ __launch_bounds__(256, 4) void gnn_layer_kernel(
    const uint32* __restrict__ ytab,
    const float* __restrict__ eA, const float* __restrict__ eB,
    const int* __restrict__ row_ptr, const int* __restrict__ csr_col,
    const float* __restrict__ sback, const float* __restrict__ dinv,
    const float* __restrict__ wout,
    const float* __restrict__ W, const float* __restrict__ b,
    const float* __restrict__ Wi, const float* __restrict__ bi,
    uint32* __restrict__ otab)
{
    __shared__ unsigned short P1s[64 * 64];   // [row][dim] bf16, byte-col ^ ((row&7)<<4)
    __shared__ unsigned short P2s[64 * 64];

    int tid = threadIdx.x;
    int lane = tid & 63;
    int wid = tid >> 6;
    int h = lane >> 5;        // edge parity
    int d2 = lane & 31;       // dim-pair index
    int base = blockIdx.x * 64;

    // ---- gather phase: 16 rows per wave ----
    for (int i = 0; i < 16; ++i) {
        int rr = wid * 16 + i;            // row-local 0..63
        int row = base + rr;
        float p1l = 0.f, p1h = 0.f, p2l = 0.f, p2h = 0.f;
        if (row < NNODE) {
            int e0 = row_ptr[row], e1 = row_ptr[row + 1];
            float aA = 0.f, aB = 0.f, aC = 0.f, aD = 0.f;
            for (int eb = e0; eb < e1; eb += 64) {
                int e = eb + lane;
                int c = NNODE; float si = 0.f;
                if (e < e1) {
                    c = csr_col[e];         // coalesced 4B
                    si = sback[c];          // hot 576KB table
                }
                int nn = min(64, e1 - eb);
                for (int k = 0; k < nn; k += 8) {
                    #pragma unroll
                    for (int u = 0; u < 4; ++u) {
                        int idx = k + 2 * u + h;          // <=63; idx>=nn lanes hold dummy
                        int cc = __shfl(c, idx);
                        float ii = __shfl(si, idx);
                        uint32 w = ytab[(size_t)cc * 32 + d2];   // 4B bf16-pair gather
                        float f0 = __uint_as_float(w << 16);
                        float f1 = __uint_as_float(w & 0xffff0000u);
                        aA += f0; aB += f1;
                        aC = fmaf(f0 * f0, ii, aC);
                        aD = fmaf(f1 * f1, ii, aD);
                    }
                }
            }
            // combine edge parities
            aA += __shfl_xor(aA, 32); aB += __shfl_xor(aB, 32);
            aC += __shfl_xor(aC, 32); aD += __shfl_xor(aD, 32);
            float dv = dinv[row];
            float xl, xh;
            if (SPLIT) {
                const float* xp = (row < USER_NUM) ? (eA + ((size_t)row << 6))
                                                   : (eB + (((size_t)row - USER_NUM) << 6));
                float2 x2 = *(const float2*)(xp + 2 * d2);
                xl = x2.x; xh = x2.y;
            } else {
                uint32 w = ytab[(size_t)row * 32 + d2];
                float s = sback[row];
                xl = __uint_as_float(w << 16) * s;
                xh = __uint_as_float(w & 0xffff0000u) * s;
            }
            p1l = fmaf(dv, aA, xl);   // (L+I)@x
            p1h = fmaf(dv, aB, xh);
            p2l = dv * aC;            // L@(x*x)
            p2h = dv * aD;
        }
        if (h == 0) {
            int cb = (4 * d2) ^ ((rr & 7) << 4);
            *(uint32*)&P1s[rr * 64 + (cb >> 1)] = packbf(p1l, p1h);
            *(uint32*)&P2s[rr * 64 + (cb >> 1)] = packbf(p2l, p2h);
        }
    }
    __syncthreads();

    // ---- MFMA phase: wave wid computes cols [16*wid, 16*wid+16) for all 64 rows ----
    int l15 = lane & 15;
    int l4  = lane >> 4;
    int n0  = wid * 16;

    bf16x8 wf[2], wif[2];
    #pragma unroll
    for (int kt = 0; kt < 2; ++kt) {
        const float* wr  = W  + (size_t)(n0 + l15) * 64 + kt * 32 + l4 * 8;
        const float* wir = Wi + (size_t)(n0 + l15) * 64 + kt * 32 + l4 * 8;
        f32x4 a0 = *(const f32x4*)wr;
        f32x4 a1 = *(const f32x4*)(wr + 4);
        f32x4 c0 = *(const f32x4*)wir;
        f32x4 c1 = *(const f32x4*)(wir + 4);
        bf16x8 t0, t1;
        #pragma unroll
        for (int j = 0; j < 4; ++j) {
            t0[j]     = (short)f2bf(a0[j]);
            t0[j + 4] = (short)f2bf(a1[j]);
            t1[j]     = (short)f2bf(c0[j]);
            t1[j + 4] = (short)f2bf(c1[j]);
        }
        wf[kt]  = t0;
        wif[kt] = t1;
    }
    float bias_v = b[n0 + l15] + bi[n0 + l15];

    f32x4 acc0 = {0.f,0.f,0.f,0.f}, acc1v = {0.f,0.f,0.f,0.f};
    f32x4 acc2v = {0.f,0.f,0.f,0.f}, acc3 = {0.f,0.f,0.f,0.f};
    f32x4* accp[4] = {&acc0, &acc1v, &acc2v, &acc3};

    #pragma unroll
    for (int mt = 0; mt < 4; ++mt) {
        #pragma unroll
        for (int kt = 0; kt < 2; ++kt) {
            int rl = mt * 16 + l15;
            int cb = (kt * 64 + l4 * 16) ^ ((rl & 7) << 4);
            int idx = rl * 64 + (cb >> 1);
            bf16x8 a1f = *(const bf16x8*)&P1s[idx];
            bf16x8 a2f = *(const bf16x8*)&P2s[idx];
            *accp[mt] = __builtin_amdgcn_mfma_f32_16x16x32_bf16(a1f, wf[kt],  *accp[mt], 0, 0, 0);
            *accp[mt] = __builtin_amdgcn_mfma_f32_16x16x32_bf16(a2f, wif[kt], *accp[mt], 0, 0, 0);
        }
    }

    // C layout: col = lane&15, row = (lane>>4)*4 + j (+ mt*16). Write packed table.
    #pragma unroll
    for (int mt = 0; mt < 4; ++mt) {
        #pragma unroll
        for (int j = 0; j < 4; ++j) {
            int r = base + mt * 16 + l4 * 4 + j;
            float o = fmaxf((*accp[mt])[j] + bias_v, 0.0f);
            float wsc = (r < NNODE) ? wout[r] : 0.0f;
            o *= wsc;
            float onb = __shfl_xor(o, 1);
            if (((l15 & 1) == 0) && r < NNODE)
                otab[(size_t)r * 32 + ((n0 + l15) >> 1)] = packbf(o, onb);
        }
    }
}

// ---------------- scoring + loss ----------------

__global__ void score_kernel(const int* __restrict__ user, const int* __restrict__ item_i,
                             const int* __restrict__ item_j,
                             const float* __restrict__ eu, const float* __restrict__ ei,
                             const uint32* __restrict__ y1b2, const uint32* __restrict__ y2b,
                             const float* __restrict__ sback,
                             float* __restrict__ out, int B)
{
    int t = blockIdx.x * 256 + threadIdx.x;
    int w = t >> 6;
    int lane = t & 63;
    if (w >= B) return;

    int u  = user[w];
    int i0 = item_i[w];
    int j0 = item_j[w];
    int ii = USER_NUM + i0;
    int jj = USER_NUM + j0;

    float e0u = eu[(size_t)u  * DDIM + lane];
    float e0i = ei[(size_t)i0 * DDIM + lane];
    float e0j = ei[(size_t)j0 * DDIM + lane];
    float di = e0u * e0i;
    float dj = e0u * e0j;

    int h = lane >> 5, d2 = lane & 31;
    const uint32* tb = h ? y2b : y1b2;
    float su = sback[u], si2 = sback[ii], sj2 = sback[jj];
    uint32 wu = tb[(size_t)u  * 32 + d2];
    uint32 wi = tb[(size_t)ii * 32 + d2];
    uint32 wj = tb[(size_t)jj * 32 + d2];
    float u0 = __uint_as_float(wu << 16) * su,   u1 = __uint_as_float(wu & 0xffff0000u) * su;
    float i0f = __uint_as_float(wi << 16) * si2, i1f = __uint_as_float(wi & 0xffff0000u) * si2;
    float j0f = __uint_as_float(wj << 16) * sj2, j1f = __uint_as_float(wj & 0xffff0000u) * sj2;
    di += u0 * i0f + u1 * i1f;
    dj += u0 * j0f + u1 * j1f;

    for (int off = 32; off; off >>= 1) {
        di += __shfl_xor(di, off);
        dj += __shfl_xor(dj, off);
    }
    if (lane == 0) {
        out[w] = di;
        out[B + w] = dj;
        float x = di - dj;
        float sp = fmaxf(-x, 0.0f) + log1pf(expf(-fabsf(x)));   // softplus(-x)
        atomicAdd(&out[2 * B], sp);
    }
}

// ---------------- launch ----------------

extern "C" void kernel_launch(void* const* d_in, const int* in_sizes, int n_in,
                              void* d_out, int out_size, void* d_ws, size_t ws_size,
                              hipStream_t stream) {
    const int*   user       = (const int*)d_in[0];
    const int*   item_i     = (const int*)d_in[1];
    const int*   item_j     = (const int*)d_in[2];
    const int*   rows       = (const int*)d_in[3];
    const int*   cols       = (const int*)d_in[4];
    const float* embed_user = (const float*)d_in[6];
    const float* embed_item = (const float*)d_in[7];
    const float* W1  = (const float*)d_in[8];
    const float* b1  = (const float*)d_in[9];
    const float* Wi1 = (const float*)d_in[10];
    const float* bi1 = (const float*)d_in[11];
    const float* W2  = (const float*)d_in[12];
    const float* b2  = (const float*)d_in[13];
    const float* Wi2 = (const float*)d_in[14];
    const float* bi2 = (const float*)d_in[15];

    int B = in_sizes[0];
    int E = in_sizes[3];
    float* out = (float*)d_out;

    char* ws = (char*)d_ws;
    size_t off = 0;
    auto alloc = [&](size_t bytes) -> void* {
        void* p = ws + off;
        off += (bytes + 255) & ~(size_t)255;
        return p;
    };
    uint32* y1b      = (uint32*)alloc((size_t)(NNODE + 1) * 32 * 4);
    uint32* y1b2     = (uint32*)alloc((size_t)(NNODE + 1) * 32 * 4);
    uint32* y2b      = (uint32*)alloc((size_t)(NNODE + 1) * 32 * 4);
    int*    row_ptr  = (int*)alloc((size_t)(NNODE + 1) * 4);
    int*    csr_col  = (int*)alloc((size_t)E * 4);
    uint32* staged   = (uint32*)alloc((size_t)E * 4);
    float*  dinv     = (float*)alloc((size_t)NNODE * 4);
    float*  wout     = (float*)alloc((size_t)NNODE * 4);
    float*  sback    = (float*)alloc((size_t)NNODE * 4);
    int*    totals   = (int*)alloc((size_t)NBUCK * 4);
    int*    bucket_off = (int*)alloc((size_t)(NBUCK + 1) * 4);
    int     nblocks  = (E + EPB - 1) / EPB;            // 245
    int*    blkcnt   = (int*)alloc((size_t)nblocks * NBUCK * 4);

    bucket_count_kernel<<<nblocks, 1024, 0, stream>>>(rows, blkcnt, E);
    bucket_block_scan_kernel<<<NBUCK, 256, 0, stream>>>(blkcnt, totals, nblocks);
    bucket_off_kernel<<<1, 1024, 0, stream>>>(totals, bucket_off, row_ptr, E);
    stage_kernel<<<nblocks, 1024, 0, stream>>>(rows, cols, blkcnt, bucket_off, staged, E);
    build_kernel<<<NBUCK, 256, 0, stream>>>(staged, bucket_off, row_ptr, csr_col,
                                            dinv, wout, sback);

    pack1_kernel<<<((NNODE + 1) * 32 + 255) / 256, 256, 0, stream>>>(
        embed_user, embed_item, dinv, y1b, y1b2, y2b);

    const int GNNB = (NNODE + 63) / 64;   // 2254
    gnn_layer_kernel<1><<<GNNB, 256, 0, stream>>>(
        y1b, embed_user, embed_item, row_ptr, csr_col, sback, dinv, wout,
        W1, b1, Wi1, bi1, y1b2);
    gnn_layer_kernel<0><<<GNNB, 256, 0, stream>>>(
        y1b2, nullptr, nullptr, row_ptr, csr_col, sback, dinv, wout,
        W2, b2, Wi2, bi2, y2b);

    init_loss_kernel<<<1, 64, 0, stream>>>(out, 2 * B);
    score_kernel<<<(B * 64 + 255) / 256, 256, 0, stream>>>(
        user, item_i, item_j, embed_user, embed_item, y1b2, y2b, sback, out, B);
}

// Round 8
// 245.618 us; speedup vs baseline: 6.4397x; 1.3635x over previous
//
#include <hip/hip_runtime.h>
#include <hip/hip_bf16.h>
#include <cmath>

#define USER_NUM 52643
#define ITEM_NUM 91599
#define NNODE (USER_NUM + ITEM_NUM)   // 144242
#define DDIM 64
#define NBUCK 564                     // ceil(NNODE/256)
#define EPB 8192                      // edges per staging block
#define BCAP 8192                     // max edges per bucket (mean ~4.9K, 47-sigma margin)

typedef unsigned int uint32;

using bf16x8 = __attribute__((ext_vector_type(8))) short;
using f32x4  = __attribute__((ext_vector_type(4))) float;

__device__ __forceinline__ uint32 f2bf(float f) {
    uint32 u = __float_as_uint(f);
    u += 0x7fffu + ((u >> 16) & 1u);   // round-to-nearest-even
    return u >> 16;
}
__device__ __forceinline__ uint32 packbf(float lo, float hi) {
    return (f2bf(hi) << 16) | f2bf(lo);
}

// ---------------- small utility kernels ----------------

__global__ void init_loss_kernel(float* __restrict__ out, int loss_idx) {
    if (threadIdx.x == 0) out[loss_idx] = 0.0f;
}

// ---------------- bucketed CSR build (all global writes dense) ----------------

// K2: per-block bucket histogram -> blkcnt[block][NBUCK]
__global__ __launch_bounds__(1024) void bucket_count_kernel(
    const int* __restrict__ rows, int* __restrict__ blkcnt, int E)
{
    __shared__ int cnt[NBUCK];
    int t = threadIdx.x;
    for (int i = t; i < NBUCK; i += 1024) cnt[i] = 0;
    __syncthreads();
    int base = blockIdx.x * EPB;
    for (int i = t; i < EPB; i += 1024) {
        int e = base + i;
        if (e < E) atomicAdd(&cnt[rows[e] >> 8], 1);
    }
    __syncthreads();
    for (int i = t; i < NBUCK; i += 1024) blkcnt[blockIdx.x * NBUCK + i] = cnt[i];
}

// K3: one block per bucket; exclusive scan of blkcnt over blocks; totals[b]
__global__ __launch_bounds__(256) void bucket_block_scan_kernel(
    int* __restrict__ blkcnt, int* __restrict__ totals, int nblocks)
{
    __shared__ int wsum[4];
    int b = blockIdx.x, t = threadIdx.x;
    int lane = t & 63, wid = t >> 6;
    int c = (t < nblocks) ? blkcnt[t * NBUCK + b] : 0;
    int v = c;
    #pragma unroll
    for (int d = 1; d < 64; d <<= 1) {
        int src = (lane >= d) ? (lane - d) : lane;
        int tmp = __shfl(v, src);
        v += (lane >= d) ? tmp : 0;
    }
    if (lane == 63) wsum[wid] = v;
    __syncthreads();
    int woff = 0;
    for (int w = 0; w < wid; ++w) woff += wsum[w];
    int excl = woff + v - c;
    if (t < nblocks) blkcnt[t * NBUCK + b] = excl;
    if (t == 255) totals[b] = excl + c;
}

// K4: exclusive scan of totals -> bucket_off (= row_ptr at bucket starts)
__global__ __launch_bounds__(1024) void bucket_off_kernel(
    const int* __restrict__ totals, int* __restrict__ bucket_off,
    int* __restrict__ row_ptr, int E)
{
    __shared__ int s[1024];
    int t = threadIdx.x;
    int v = (t < NBUCK) ? totals[t] : 0;
    s[t] = v;
    __syncthreads();
    #pragma unroll
    for (int d = 1; d < 1024; d <<= 1) {
        int add = (t >= d) ? s[t - d] : 0;
        __syncthreads();
        s[t] += add;
        __syncthreads();
    }
    if (t < NBUCK) bucket_off[t] = s[t] - v;
    if (t == 0) { bucket_off[NBUCK] = E; row_ptr[NNODE] = E; }
}

// K5: stage edges into bucket slices, packed (r&255)<<18 | col (dense-ish writes)
__global__ __launch_bounds__(1024) void stage_kernel(
    const int* __restrict__ rows, const int* __restrict__ cols,
    const int* __restrict__ blkcnt, const int* __restrict__ bucket_off,
    uint32* __restrict__ staged, int E)
{
    __shared__ int cnt[NBUCK];
    __shared__ int basel[NBUCK];
    int t = threadIdx.x;
    for (int i = t; i < NBUCK; i += 1024) {
        cnt[i] = 0;
        basel[i] = bucket_off[i] + blkcnt[blockIdx.x * NBUCK + i];
    }
    __syncthreads();
    int base = blockIdx.x * EPB;
    for (int i = t; i < EPB; i += 1024) {
        int e = base + i;
        if (e < E) {
            int r = rows[e];
            int bkt = r >> 8;
            int rank = atomicAdd(&cnt[bkt], 1);
            staged[basel[bkt] + rank] = ((uint32)(r & 255) << 18) | (uint32)cols[e];
        }
    }
}

// K6: one block per bucket: derive degrees (-> row_ptr, dinv, wout, sback),
// LDS-order the cols, stream out csr_col densely.
__global__ __launch_bounds__(256) void build_kernel(
    const uint32* __restrict__ staged, const int* __restrict__ bucket_off,
    int* __restrict__ row_ptr, int* __restrict__ csr_col,
    float* __restrict__ dinv, float* __restrict__ wout, float* __restrict__ sback)
{
    __shared__ int cnt[256];
    __shared__ int off[256];
    __shared__ int wsum[4];
    __shared__ int colbuf[BCAP];
    int b = blockIdx.x, t = threadIdx.x;
    int lane = t & 63, wid = t >> 6;
    int eoff = bucket_off[b];
    int ecnt = bucket_off[b + 1] - eoff;

    cnt[t] = 0;
    __syncthreads();
    for (int i = t; i < ecnt; i += 256) atomicAdd(&cnt[staged[eoff + i] >> 18], 1);
    __syncthreads();

    int c = cnt[t];
    int v = c;
    #pragma unroll
    for (int d = 1; d < 64; d <<= 1) {
        int src = (lane >= d) ? (lane - d) : lane;
        int tmp = __shfl(v, src);
        v += (lane >= d) ? tmp : 0;
    }
    if (lane == 63) wsum[wid] = v;
    __syncthreads();
    int woff = 0;
    for (int w = 0; w < wid; ++w) woff += wsum[w];
    int excl = woff + v - c;
    off[t] = excl;

    int node = b * 256 + t;
    if (node < NNODE) {
        row_ptr[node] = eoff + excl;
        float df = (float)c;
        float dv = (c > 0) ? (1.0f / sqrtf(df)) : 0.0f;
        dinv[node]  = dv;
        wout[node]  = (c > 0) ? dv : 1.0f;
        sback[node] = (c > 0) ? sqrtf(df) : 1.0f;
    }
    __syncthreads();
    cnt[t] = 0;
    __syncthreads();
    for (int i = t; i < ecnt; i += 256) {
        uint32 w = staged[eoff + i];
        int rl = w >> 18;
        int rank = atomicAdd(&cnt[rl], 1);
        colbuf[off[rl] + rank] = (int)(w & 0x3FFFFu);
    }
    __syncthreads();
    for (int i = t; i < ecnt; i += 256) csr_col[eoff + i] = colbuf[i];
}

// pack layer-1 gather table: y1b[n][d2] = bf16pair(dinv*x[2d2], dinv*x[2d2+1]); zero dummy row
__global__ void pack1_kernel(const float* __restrict__ eu, const float* __restrict__ ei,
                             const float* __restrict__ dinv,
                             uint32* __restrict__ y1b, uint32* __restrict__ y1b2,
                             uint32* __restrict__ y2b) {
    int t = blockIdx.x * 256 + threadIdx.x;     // t = n*32 + d2
    int n = t >> 5, d2 = t & 31;
    if (n > NNODE) return;
    if (n == NNODE) { y1b[t] = 0; y1b2[t] = 0; y2b[t] = 0; return; }
    const float* xp = (n < USER_NUM) ? (eu + ((size_t)n << 6))
                                     : (ei + (((size_t)n - USER_NUM) << 6));
    float2 x2 = *(const float2*)(xp + 2 * d2);
    float dv = dinv[n];
    y1b[t] = packbf(dv * x2.x, dv * x2.y);
    (void)d2;
}

// ---------------- fused GNN layer ----------------
// Gather: pair-mode — lane l handles dim-pair (l&31) of edge parity (l>>5);
// one 4B bf16-pair gather per edge covers both y1-dims; p2 via y^2*sback_c.
// Tail lanes use dummy row NNODE (zeros). Epilogue: MFMA, writes packed table.

template <int SPLIT>
__global__ __launch_bounds__(256, 4) void gnn_layer_kernel(
    const uint32* __restrict__ ytab,
    const float* __restrict__ eA, const float* __restrict__ eB,
    const int* __restrict__ row_ptr, const int* __restrict__ csr_col,
    const float* __restrict__ sback, const float* __restrict__ dinv,
    const float* __restrict__ wout,
    const float* __restrict__ W, const float* __restrict__ b,
    const float* __restrict__ Wi, const float* __restrict__ bi,
    uint32* __restrict__ otab)
{
    __shared__ unsigned short P1s[64 * 64];   // [row][dim] bf16, byte-col ^ ((row&7)<<4)
    __shared__ unsigned short P2s[64 * 64];

    int tid = threadIdx.x;
    int lane = tid & 63;
    int wid = tid >> 6;
    int h = lane >> 5;        // edge parity
    int d2 = lane & 31;       // dim-pair index
    int base = blockIdx.x * 64;

    // ---- gather phase: 16 rows per wave ----
    for (int i = 0; i < 16; ++i) {
        int rr = wid * 16 + i;            // row-local 0..63
        int row = base + rr;
        float p1l = 0.f, p1h = 0.f, p2l = 0.f, p2h = 0.f;
        if (row < NNODE) {
            int e0 = row_ptr[row], e1 = row_ptr[row + 1];
            float aA = 0.f, aB = 0.f, aC = 0.f, aD = 0.f;
            for (int eb = e0; eb < e1; eb += 64) {
                int e = eb + lane;
                int c = NNODE; float si = 0.f;
                if (e < e1) {
                    c = csr_col[e];         // coalesced 4B
                    si = sback[c];          // hot 576KB table
                }
                int nn = min(64, e1 - eb);
                for (int k = 0; k < nn; k += 8) {
                    #pragma unroll
                    for (int u = 0; u < 4; ++u) {
                        int idx = k + 2 * u + h;          // <=63; idx>=nn lanes hold dummy
                        int cc = __shfl(c, idx);
                        float ii = __shfl(si, idx);
                        uint32 w = ytab[(size_t)cc * 32 + d2];   // 4B bf16-pair gather
                        float f0 = __uint_as_float(w << 16);
                        float f1 = __uint_as_float(w & 0xffff0000u);
                        aA += f0; aB += f1;
                        aC = fmaf(f0 * f0, ii, aC);
                        aD = fmaf(f1 * f1, ii, aD);
                    }
                }
            }
            // combine edge parities
            aA += __shfl_xor(aA, 32); aB += __shfl_xor(aB, 32);
            aC += __shfl_xor(aC, 32); aD += __shfl_xor(aD, 32);
            float dv = dinv[row];
            float xl, xh;
            if (SPLIT) {
                const float* xp = (row < USER_NUM) ? (eA + ((size_t)row << 6))
                                                   : (eB + (((size_t)row - USER_NUM) << 6));
                float2 x2 = *(const float2*)(xp + 2 * d2);
                xl = x2.x; xh = x2.y;
            } else {
                uint32 w = ytab[(size_t)row * 32 + d2];
                float s = sback[row];
                xl = __uint_as_float(w << 16) * s;
                xh = __uint_as_float(w & 0xffff0000u) * s;
            }
            p1l = fmaf(dv, aA, xl);   // (L+I)@x
            p1h = fmaf(dv, aB, xh);
            p2l = dv * aC;            // L@(x*x)
            p2h = dv * aD;
        }
        if (h == 0) {
            int cb = (4 * d2) ^ ((rr & 7) << 4);
            *(uint32*)&P1s[rr * 64 + (cb >> 1)] = packbf(p1l, p1h);
            *(uint32*)&P2s[rr * 64 + (cb >> 1)] = packbf(p2l, p2h);
        }
    }
    __syncthreads();

    // ---- MFMA phase: wave wid computes cols [16*wid, 16*wid+16) for all 64 rows ----
    int l15 = lane & 15;
    int l4  = lane >> 4;
    int n0  = wid * 16;

    bf16x8 wf[2], wif[2];
    #pragma unroll
    for (int kt = 0; kt < 2; ++kt) {
        const float* wr  = W  + (size_t)(n0 + l15) * 64 + kt * 32 + l4 * 8;
        const float* wir = Wi + (size_t)(n0 + l15) * 64 + kt * 32 + l4 * 8;
        f32x4 a0 = *(const f32x4*)wr;
        f32x4 a1 = *(const f32x4*)(wr + 4);
        f32x4 c0 = *(const f32x4*)wir;
        f32x4 c1 = *(const f32x4*)(wir + 4);
        bf16x8 t0, t1;
        #pragma unroll
        for (int j = 0; j < 4; ++j) {
            t0[j]     = (short)f2bf(a0[j]);
            t0[j + 4] = (short)f2bf(a1[j]);
            t1[j]     = (short)f2bf(c0[j]);
            t1[j + 4] = (short)f2bf(c1[j]);
        }
        wf[kt]  = t0;
        wif[kt] = t1;
    }
    float bias_v = b[n0 + l15] + bi[n0 + l15];

    f32x4 acc0 = {0.f,0.f,0.f,0.f}, acc1v = {0.f,0.f,0.f,0.f};
    f32x4 acc2v = {0.f,0.f,0.f,0.f}, acc3 = {0.f,0.f,0.f,0.f};
    f32x4* accp[4] = {&acc0, &acc1v, &acc2v, &acc3};

    #pragma unroll
    for (int mt = 0; mt < 4; ++mt) {
        #pragma unroll
        for (int kt = 0; kt < 2; ++kt) {
            int rl = mt * 16 + l15;
            int cb = (kt * 64 + l4 * 16) ^ ((rl & 7) << 4);
            int idx = rl * 64 + (cb >> 1);
            bf16x8 a1f = *(const bf16x8*)&P1s[idx];
            bf16x8 a2f = *(const bf16x8*)&P2s[idx];
            *accp[mt] = __builtin_amdgcn_mfma_f32_16x16x32_bf16(a1f, wf[kt],  *accp[mt], 0, 0, 0);
            *accp[mt] = __builtin_amdgcn_mfma_f32_16x16x32_bf16(a2f, wif[kt], *accp[mt], 0, 0, 0);
        }
    }

    // C layout: col = lane&15, row = (lane>>4)*4 + j (+ mt*16). Write packed table.
    #pragma unroll
    for (int mt = 0; mt < 4; ++mt) {
        #pragma unroll
        for (int j = 0; j < 4; ++j) {
            int r = base + mt * 16 + l4 * 4 + j;
            float o = fmaxf((*accp[mt])[j] + bias_v, 0.0f);
            float wsc = (r < NNODE) ? wout[r] : 0.0f;
            o *= wsc;
            float onb = __shfl_xor(o, 1);
            if (((l15 & 1) == 0) && r < NNODE)
                otab[(size_t)r * 32 + ((n0 + l15) >> 1)] = packbf(o, onb);
        }
    }
}

// ---------------- scoring + loss ----------------
// Each wave grid-strides over samples (8 per wave), accumulates softplus partial
// in-register; one atomicAdd per block (256 total, vs 8192 same-address before).

__global__ __launch_bounds__(256) void score_kernel(
    const int* __restrict__ user, const int* __restrict__ item_i,
    const int* __restrict__ item_j,
    const float* __restrict__ eu, const float* __restrict__ ei,
    const uint32* __restrict__ y1b2, const uint32* __restrict__ y2b,
    const float* __restrict__ sback,
    float* __restrict__ out, int B, int nwaves)
{
    int tid = threadIdx.x;
    int lane = tid & 63;
    int wv = tid >> 6;
    int gw = blockIdx.x * 4 + wv;
    int h = lane >> 5, d2 = lane & 31;

    float spacc = 0.0f;
    for (int w = gw; w < B; w += nwaves) {
        int u  = user[w];
        int i0 = item_i[w];
        int j0 = item_j[w];
        int ii = USER_NUM + i0;
        int jj = USER_NUM + j0;

        float e0u = eu[(size_t)u  * DDIM + lane];
        float e0i = ei[(size_t)i0 * DDIM + lane];
        float e0j = ei[(size_t)j0 * DDIM + lane];
        float di = e0u * e0i;
        float dj = e0u * e0j;

        const uint32* tb = h ? y2b : y1b2;
        float su = sback[u], si2 = sback[ii], sj2 = sback[jj];
        uint32 wu = tb[(size_t)u  * 32 + d2];
        uint32 wi = tb[(size_t)ii * 32 + d2];
        uint32 wj = tb[(size_t)jj * 32 + d2];
        float u0 = __uint_as_float(wu << 16) * su,   u1 = __uint_as_float(wu & 0xffff0000u) * su;
        float i0f = __uint_as_float(wi << 16) * si2, i1f = __uint_as_float(wi & 0xffff0000u) * si2;
        float j0f = __uint_as_float(wj << 16) * sj2, j1f = __uint_as_float(wj & 0xffff0000u) * sj2;
        di += u0 * i0f + u1 * i1f;
        dj += u0 * j0f + u1 * j1f;

        for (int off = 32; off; off >>= 1) {
            di += __shfl_xor(di, off);
            dj += __shfl_xor(dj, off);
        }
        if (lane == 0) {
            out[w] = di;
            out[B + w] = dj;
            float x = di - dj;
            spacc += fmaxf(-x, 0.0f) + log1pf(expf(-fabsf(x)));   // softplus(-x)
        }
    }

    __shared__ float sred[4];
    if (lane == 0) sred[wv] = spacc;
    __syncthreads();
    if (tid == 0)
        atomicAdd(&out[2 * B], sred[0] + sred[1] + sred[2] + sred[3]);
}

// ---------------- launch ----------------

extern "C" void kernel_launch(void* const* d_in, const int* in_sizes, int n_in,
                              void* d_out, int out_size, void* d_ws, size_t ws_size,
                              hipStream_t stream) {
    const int*   user       = (const int*)d_in[0];
    const int*   item_i     = (const int*)d_in[1];
    const int*   item_j     = (const int*)d_in[2];
    const int*   rows       = (const int*)d_in[3];
    const int*   cols       = (const int*)d_in[4];
    const float* embed_user = (const float*)d_in[6];
    const float* embed_item = (const float*)d_in[7];
    const float* W1  = (const float*)d_in[8];
    const float* b1  = (const float*)d_in[9];
    const float* Wi1 = (const float*)d_in[10];
    const float* bi1 = (const float*)d_in[11];
    const float* W2  = (const float*)d_in[12];
    const float* b2  = (const float*)d_in[13];
    const float* Wi2 = (const float*)d_in[14];
    const float* bi2 = (const float*)d_in[15];

    int B = in_sizes[0];
    int E = in_sizes[3];
    float* out = (float*)d_out;

    char* ws = (char*)d_ws;
    size_t off = 0;
    auto alloc = [&](size_t bytes) -> void* {
        void* p = ws + off;
        off += (bytes + 255) & ~(size_t)255;
        return p;
    };
    uint32* y1b      = (uint32*)alloc((size_t)(NNODE + 1) * 32 * 4);
    uint32* y1b2     = (uint32*)alloc((size_t)(NNODE + 1) * 32 * 4);
    uint32* y2b      = (uint32*)alloc((size_t)(NNODE + 1) * 32 * 4);
    int*    row_ptr  = (int*)alloc((size_t)(NNODE + 1) * 4);
    int*    csr_col  = (int*)alloc((size_t)E * 4);
    uint32* staged   = (uint32*)alloc((size_t)E * 4);
    float*  dinv     = (float*)alloc((size_t)NNODE * 4);
    float*  wout     = (float*)alloc((size_t)NNODE * 4);
    float*  sback    = (float*)alloc((size_t)NNODE * 4);
    int*    totals   = (int*)alloc((size_t)NBUCK * 4);
    int*    bucket_off = (int*)alloc((size_t)(NBUCK + 1) * 4);
    int     nblocks  = (E + EPB - 1) / EPB;            // 245
    int*    blkcnt   = (int*)alloc((size_t)nblocks * NBUCK * 4);

    bucket_count_kernel<<<nblocks, 1024, 0, stream>>>(rows, blkcnt, E);
    bucket_block_scan_kernel<<<NBUCK, 256, 0, stream>>>(blkcnt, totals, nblocks);
    bucket_off_kernel<<<1, 1024, 0, stream>>>(totals, bucket_off, row_ptr, E);
    stage_kernel<<<nblocks, 1024, 0, stream>>>(rows, cols, blkcnt, bucket_off, staged, E);
    build_kernel<<<NBUCK, 256, 0, stream>>>(staged, bucket_off, row_ptr, csr_col,
                                            dinv, wout, sback);

    pack1_kernel<<<((NNODE + 1) * 32 + 255) / 256, 256, 0, stream>>>(
        embed_user, embed_item, dinv, y1b, y1b2, y2b);

    const int GNNB = (NNODE + 63) / 64;   // 2254
    gnn_layer_kernel<1><<<GNNB, 256, 0, stream>>>(
        y1b, embed_user, embed_item, row_ptr, csr_col, sback, dinv, wout,
        W1, b1, Wi1, bi1, y1b2);
    gnn_layer_kernel<0><<<GNNB, 256, 0, stream>>>(
        y1b2, nullptr, nullptr, row_ptr, csr_col, sback, dinv, wout,
        W2, b2, Wi2, bi2, y2b);

    init_loss_kernel<<<1, 64, 0, stream>>>(out, 2 * B);
    const int SCORE_BLOCKS = 256;                      // 1024 waves, 8 samples each
    score_kernel<<<SCORE_BLOCKS, 256, 0, stream>>>(
        user, item_i, item_j, embed_user, embed_item, y1b2, y2b, sback,
        out, B, SCORE_BLOCKS * 4);
}